// Round 15
// baseline (232.648 us; speedup 1.0000x reference)
//
#include <hip/hip_runtime.h>

constexpr int B = 4, S = 2048, U = 1024, H = 16, DH = 64;
constexpr int MTOT = B * S;
constexpr int NT = S / 64;   // 32 key-tiles of 64

using bf16   = __bf16;
using f32x4  = __attribute__((ext_vector_type(4))) float;
using f32x16 = __attribute__((ext_vector_type(16))) float;
using bf16x8 = __attribute__((ext_vector_type(8))) bf16;
using bf16x4 = __attribute__((ext_vector_type(4))) bf16;
using u32x4  = __attribute__((ext_vector_type(4))) unsigned int;

__device__ __forceinline__ void gload16(const bf16* g, bf16* l) {
  __builtin_amdgcn_global_load_lds(
      (const __attribute__((address_space(1))) unsigned int*)g,
      (__attribute__((address_space(3))) unsigned int*)l, 16, 0, 0);
}

__device__ __forceinline__ float fexp2(float x) {
#if __has_builtin(__builtin_amdgcn_exp2f)
  return __builtin_amdgcn_exp2f(x);
#else
  return __expf(x * 0.6931471805599453f);
#endif
}

__device__ __forceinline__ f32x16 mfma32(bf16x8 a, bf16x8 b, f32x16 c) {
  return __builtin_amdgcn_mfma_f32_32x32x16_bf16(a, b, c, 0, 0, 0);
}

__device__ __forceinline__ unsigned packbf(float a, float b) {
  union { bf16 h; unsigned short s; } ua, ub;
  ua.h = (bf16)a; ub.h = (bf16)b;
  return ((unsigned)ub.s << 16) | (unsigned)ua.s;
}

// packed K layout: Kp[bh][t][tt][ks][ln][8] = K[s = t*64+tt*32+(ln&31)][h*64 + ks*16+(ln>>5)*8+j]
__device__ __forceinline__ size_t kpack_off(int M_, int col) {
  const int b = M_ >> 11, s = M_ & 2047;
  const int h = col >> 6, d = col & 63;
  const int bh = b * 16 + h;
  const int t = s >> 6, r64 = s & 63;
  const int tt = r64 >> 5, l31 = r64 & 31;
  const int ks = d >> 4, hi = (d >> 3) & 1, j = d & 7;
  const int ln = l31 + (hi << 5);
  return ((size_t)(bh * 32 + t) << 12) + (tt << 11) + (ks << 9) + (ln << 3) + j;
}

// packed V layout: Vp[bh][t][dt][ks][ln][8] = V[s = t*64+ks*16+(ln>>5)*8+j][h*64 + dt*32+(ln&31)]
__device__ __forceinline__ size_t vpack_off(int M_, int col) {
  const int b = M_ >> 11, s = M_ & 2047;
  const int h = col >> 6, d = col & 63;
  const int bh = b * 16 + h;
  const int j = s & 7, hi = (s >> 3) & 1, ks = (s >> 4) & 3, t = s >> 6;
  const int dt = d >> 5, l31 = d & 31;
  const int ln = l31 + (hi << 5);
  return ((size_t)(bh * 32 + t) << 12) + (dt << 11) + (ks << 9) + (ln << 3) + j;
}

// ---------- prep: fused {fp32->bf16 convert of q,k,v} + {4x weight transpose+convert} ----------
__global__ __launch_bounds__(256) void prep_kernel(
    const float* __restrict__ xq, const float* __restrict__ xk, const float* __restrict__ xv,
    bf16* __restrict__ oq, bf16* __restrict__ ok, bf16* __restrict__ ov,
    const float* __restrict__ w0, const float* __restrict__ w1,
    const float* __restrict__ w2, const float* __restrict__ w3,
    bf16* __restrict__ t0, bf16* __restrict__ t1,
    bf16* __restrict__ t2, bf16* __restrict__ t3) {
  __shared__ float tile[32][33];
  const int bid = blockIdx.x;
  const int t = threadIdx.x;
  if (bid < 12288) {
    const int z = bid >> 12, idx = bid & 4095;
    const float* x = z == 0 ? xq : z == 1 ? xk : xv;
    bf16* o       = z == 0 ? oq : z == 1 ? ok : ov;
    const size_t i = ((size_t)idx * 256 + t) * 8;
    const float4 v0 = *reinterpret_cast<const float4*>(x + i);
    const float4 v1 = *reinterpret_cast<const float4*>(x + i + 4);
    bf16x8 r;
    r[0] = (bf16)v0.x; r[1] = (bf16)v0.y; r[2] = (bf16)v0.z; r[3] = (bf16)v0.w;
    r[4] = (bf16)v1.x; r[5] = (bf16)v1.y; r[6] = (bf16)v1.z; r[7] = (bf16)v1.w;
    *reinterpret_cast<bf16x8*>(o + i) = r;
  } else {
    const int wb = bid - 12288;
    const int z = wb >> 10, ti = wb & 1023;
    const float* W = z == 0 ? w0 : z == 1 ? w1 : z == 2 ? w2 : w3;
    bf16* Wt       = z == 0 ? t0 : z == 1 ? t1 : z == 2 ? t2 : t3;
    const int k0 = (ti & 31) * 32, n0 = (ti >> 5) * 32;
    const int tx = t & 31, ty = t >> 5;
    for (int i = ty; i < 32; i += 8) tile[i][tx] = W[(size_t)(k0 + i) * U + n0 + tx];
    __syncthreads();
    for (int i = ty; i < 32; i += 8) Wt[(size_t)(n0 + i) * U + k0 + tx] = (bf16)tile[tx][i];
  }
}

// ---------- fused 4-GEMM: out = relu(A @ Wt^T + b) ----------
// 128^2 tile, 4 waves 2x2. Depth-2 double-buffered pipeline at BK=32 granularity:
// stage(buf, k+64) issued one full phase before its counted wait; vmcnt(4) keeps the
// newest 4 loads in flight across the barrier (never drains to 0 mid-loop).
// LDS stays 32KB (same occupancy as r12); buffer addresses compile-time.
// r9-verified two-sided slot swizzle + XCD-chunk swizzle (n fastest).
__global__ __launch_bounds__(256) void gemm4_kernel(
    const bf16* __restrict__ Qc, const bf16* __restrict__ Kc, const bf16* __restrict__ Vc,
    const bf16* __restrict__ wqt, const bf16* __restrict__ wkt,
    const bf16* __restrict__ wvt, const bf16* __restrict__ wrt,
    const float* __restrict__ bq, const float* __restrict__ bk,
    const float* __restrict__ bv, const float* __restrict__ br,
    bf16* __restrict__ oq, bf16* __restrict__ okp,
    bf16* __restrict__ ovp, bf16* __restrict__ orr) {
  const int bid = blockIdx.x;
  const int wg = (bid & 7) * 256 + (bid >> 3);   // bijective: 2048 % 8 == 0
  const int z = wg >> 9, rem = wg & 511;
  const int bm = (rem >> 3) * 128, bn = (rem & 7) * 128;

  const bf16* A     = z == 0 ? Qc : z == 1 ? Kc : Vc;   // z==2,3 read Vcvt
  const bf16* Wt    = z == 0 ? wqt : z == 1 ? wkt : z == 2 ? wvt : wrt;
  const float* bias = z == 0 ? bq : z == 1 ? bk : z == 2 ? bv : br;

  const int t = threadIdx.x, lane = t & 63, wid = t >> 6;
  const int wr = wid >> 1, wc = wid & 1;
  const int lm = lane & 15, hi = lane >> 4;

  __shared__ __align__(16) bf16 As[2][128][32];   // 16KB
  __shared__ __align__(16) bf16 Bs[2][128][32];   // 16KB

  f32x4 acc[4][4];
#pragma unroll
  for (int i = 0; i < 4; ++i)
#pragma unroll
    for (int j = 0; j < 4; ++j) acc[i][j] = f32x4{0.f, 0.f, 0.f, 0.f};

  // staging: LDS dest LINEAR; source col pre-swizzled so LDS slot s of row r holds
  // data slot s ^ ((r>>1)&3)  [r9-verified].
  const int srow = wid * 32 + (lane >> 2);
  const int scol = ((lane & 3) ^ ((lane >> 3) & 3)) * 8;
  const bf16* ga = A  + (size_t)(bm + srow) * U + scol;
  const bf16* gb = Wt + (size_t)(bn + srow) * U + scol;

  auto stage = [&](bf16 (*A_)[32], bf16 (*B_)[32], int k0) {
    gload16(ga + k0,                  &A_[wid * 32][0]);
    gload16(ga + (size_t)16 * U + k0, &A_[wid * 32 + 16][0]);
    gload16(gb + k0,                  &B_[wid * 32][0]);
    gload16(gb + (size_t)16 * U + k0, &B_[wid * 32 + 16][0]);
  };

  // fragment-read slot: data slot hi of row (..+lm) lives at slot hi ^ ((lm>>1)&3)
  const int sw = (hi ^ ((lm >> 1) & 3)) * 8;

  auto compute = [&](const bf16 (*A_)[32], const bf16 (*B_)[32]) {
    bf16x8 a[4], bb[4];
#pragma unroll
    for (int mi = 0; mi < 4; ++mi)
      a[mi] = *reinterpret_cast<const bf16x8*>(&A_[wr * 64 + mi * 16 + lm][sw]);
#pragma unroll
    for (int ni = 0; ni < 4; ++ni)
      bb[ni] = *reinterpret_cast<const bf16x8*>(&B_[wc * 64 + ni * 16 + lm][sw]);
#pragma unroll
    for (int mi = 0; mi < 4; ++mi)
#pragma unroll
      for (int ni = 0; ni < 4; ++ni)
        acc[mi][ni] = __builtin_amdgcn_mfma_f32_16x16x32_bf16(a[mi], bb[ni], acc[mi][ni], 0, 0, 0);
  };

  // prologue: buf0 ready, buf1 in flight
  stage(As[0], Bs[0], 0);
  asm volatile("s_waitcnt vmcnt(0)" ::: "memory");
  __builtin_amdgcn_s_barrier();
  __builtin_amdgcn_sched_barrier(0);
  stage(As[1], Bs[1], 32);

  for (int k0 = 0; k0 < U; k0 += 64) {
    compute(As[0], Bs[0]);                               // k = k0 (landed + barriered)
    asm volatile("s_waitcnt lgkmcnt(0)" ::: "memory");
    __builtin_amdgcn_s_barrier();                        // all waves done reading buf0
    __builtin_amdgcn_sched_barrier(0);
    if (k0 + 64 < U) {
      stage(As[0], Bs[0], k0 + 64);                      // refill buf0 (in flight: buf1 4 + buf0 4)
      asm volatile("s_waitcnt vmcnt(4)" ::: "memory");   // buf1 (k0+32) landed; buf0-new stays in flight
    } else {
      asm volatile("s_waitcnt vmcnt(0)" ::: "memory");   // tail: drain (issued a phase ago)
    }
    __builtin_amdgcn_s_barrier();
    __builtin_amdgcn_sched_barrier(0);

    compute(As[1], Bs[1]);                               // k = k0 + 32
    asm volatile("s_waitcnt lgkmcnt(0)" ::: "memory");
    __builtin_amdgcn_s_barrier();                        // all waves done reading buf1
    __builtin_amdgcn_sched_barrier(0);
    if (k0 + 96 < U) {
      stage(As[1], Bs[1], k0 + 96);
      asm volatile("s_waitcnt vmcnt(4)" ::: "memory");   // buf0 (k0+64) landed
    } else {
      asm volatile("s_waitcnt vmcnt(0)" ::: "memory");
    }
    __builtin_amdgcn_s_barrier();
    __builtin_amdgcn_sched_barrier(0);
  }

  const int mb = bm + wr * 64 + hi * 4;
  const int nb = bn + wc * 64 + lm;
  if (z == 1) {
#pragma unroll
    for (int ni = 0; ni < 4; ++ni) {
      const float bv_ = bias[nb + ni * 16];
#pragma unroll
      for (int mi = 0; mi < 4; ++mi)
#pragma unroll
        for (int r = 0; r < 4; ++r) {
          const float vv = fmaxf(acc[mi][ni][r] + bv_, 0.f);
          okp[kpack_off(mb + mi * 16 + r, nb + ni * 16)] = (bf16)vv;
        }
    }
  } else if (z == 2) {
#pragma unroll
    for (int ni = 0; ni < 4; ++ni) {
      const float bv_ = bias[nb + ni * 16];
#pragma unroll
      for (int mi = 0; mi < 4; ++mi)
#pragma unroll
        for (int r = 0; r < 4; ++r) {
          const float vv = fmaxf(acc[mi][ni][r] + bv_, 0.f);
          ovp[vpack_off(mb + mi * 16 + r, nb + ni * 16)] = (bf16)vv;
        }
    }
  } else {
    bf16* out = z == 0 ? oq : orr;
#pragma unroll
    for (int ni = 0; ni < 4; ++ni) {
      const float bv_ = bias[nb + ni * 16];
#pragma unroll
      for (int mi = 0; mi < 4; ++mi)
#pragma unroll
        for (int r = 0; r < 4; ++r) {
          const float vv = fmaxf(acc[mi][ni][r] + bv_, 0.f);
          out[(size_t)(mb + mi * 16 + r) * U + nb + ni * 16] = (bf16)vv;
        }
    }
  }
}

// ---------- flash attention: packed K/V, 2-buffer LDS pipeline (32KB) ----------
// 4 waves x 32 q-rows. Swapped QK^T (32x32x16); no-max softmax (r13/r14-verified);
// denominator via ones-MFMA; half-exchange via v_permlane32_swap_b32.
__global__ __launch_bounds__(256, 2) void attn_kernel(
    const bf16* __restrict__ Q, const bf16* __restrict__ Kp,
    const bf16* __restrict__ Vp, bf16* __restrict__ att) {
  const int bid = blockIdx.x;
  const int swz = (bid & 7) * 128 + (bid >> 3);     // 8 bh per XCD
  const int bh = swz >> 4, qx = swz & 15;
  const int b = bh >> 4, h = bh & 15;
  const int tid = threadIdx.x;
  const int w = tid >> 6, lane = tid & 63;
  const int l31 = lane & 31, hi8 = lane >> 5;
  const int q0 = qx * 128 + w * 32;

  __shared__ __align__(16) bf16 kv[2][8192];   // [0..4095]=K tile, [4096..8191]=V tile

  const float qscale = 0.18033688011111606f;  // log2(e)/sqrt(DH)

  // Q fragments (B operand: col = q = l31, contraction = dh)
  const bf16* qbase = Q + ((size_t)b * S + q0 + l31) * U + h * DH + hi8 * 8;
  bf16x8 qf[4];
#pragma unroll
  for (int ks = 0; ks < 4; ++ks) {
    bf16x8 v = *reinterpret_cast<const bf16x8*>(qbase + ks * 16);
#pragma unroll
    for (int j = 0; j < 8; ++j) v[j] = (bf16)((float)v[j] * qscale);
    qf[ks] = v;
  }

  bf16x8 onesf;
#pragma unroll
  for (int j = 0; j < 8; ++j) onesf[j] = (bf16)1.f;

  f32x16 o0 = (f32x16)0.f, o1 = (f32x16)0.f, osum = (f32x16)0.f;

  const bf16* kpb = Kp + (size_t)bh * 32 * 4096;
  const bf16* vpb = Vp + (size_t)bh * 32 * 4096;

  auto stagekv = [&](int buf, int t) {
    const size_t toff = (size_t)t * 4096;
    gload16(kpb + toff + tid * 8,        &kv[buf][tid * 8]);
    gload16(kpb + toff + 2048 + tid * 8, &kv[buf][2048 + tid * 8]);
    gload16(vpb + toff + tid * 8,        &kv[buf][4096 + tid * 8]);
    gload16(vpb + toff + 2048 + tid * 8, &kv[buf][6144 + tid * 8]);
  };

  stagekv(0, 0);
  asm volatile("s_waitcnt vmcnt(0)" ::: "memory");
  __builtin_amdgcn_s_barrier();
  __builtin_amdgcn_sched_barrier(0);

  for (int t = 0; t < NT; ++t) {
    const int cur = t & 1;
    if (t + 1 < NT) stagekv(cur ^ 1, t + 1);

    bf16x8 kf[2][4];
#pragma unroll
    for (int tt = 0; tt < 2; ++tt)
#pragma unroll
      for (int ks = 0; ks < 4; ++ks)
        kf[tt][ks] = *reinterpret_cast<const bf16x8*>(&kv[cur][(tt * 4 + ks) * 512 + lane * 8]);

    // S^T = K Q^T : rows = k, cols = q (l31)
    f32x16 s0 = (f32x16)0.f, s1 = (f32x16)0.f;
    __builtin_amdgcn_s_setprio(1);
#pragma unroll
    for (int ks = 0; ks < 4; ++ks) {
      s0 = mfma32(kf[0][ks], qf[ks], s0);
      s1 = mfma32(kf[1][ks], qf[ks], s1);
    }
    __builtin_amdgcn_s_setprio(0);

    bf16x8 vf[2][4];
#pragma unroll
    for (int dt = 0; dt < 2; ++dt)
#pragma unroll
      for (int ks = 0; ks < 4; ++ks)
        vf[dt][ks] = *reinterpret_cast<const bf16x8*>(&kv[cur][4096 + (dt * 4 + ks) * 512 + lane * 8]);

    // P = exp2(s) lane-local; pack to bf16 pairs (no max subtraction needed)
    unsigned wpk[16];
#pragma unroll
    for (int i = 0; i < 8; ++i) {
      wpk[i]     = packbf(fexp2(s0[2 * i]), fexp2(s0[2 * i + 1]));
      wpk[8 + i] = packbf(fexp2(s1[2 * i]), fexp2(s1[2 * i + 1]));
    }

    // half-exchange via permlane32_swap
    u32x4 fw[4];
#pragma unroll
    for (int fi = 0; fi < 4; ++fi) {
      unsigned a0 = wpk[fi * 4 + 0], b0 = wpk[fi * 4 + 2];
      unsigned a1 = wpk[fi * 4 + 1], b1 = wpk[fi * 4 + 3];
      asm("v_permlane32_swap_b32 %0, %1" : "+v"(a0), "+v"(b0));
      asm("v_permlane32_swap_b32 %0, %1" : "+v"(a1), "+v"(b1));
      fw[fi] = u32x4{a0, a1, b0, b1};
    }

    // O += P V ; row-sum += P * ones  (denominator in the matrix pipe, same C layout)
    __builtin_amdgcn_s_setprio(1);
#pragma unroll
    for (int ks = 0; ks < 4; ++ks) {
      const bf16x8 pf = __builtin_bit_cast(bf16x8, fw[ks]);
      o0   = mfma32(pf, vf[0][ks], o0);
      o1   = mfma32(pf, vf[1][ks], o1);
      osum = mfma32(pf, onesf, osum);
    }
    __builtin_amdgcn_s_setprio(0);

    if (t + 1 < NT) {
      asm volatile("s_waitcnt vmcnt(0)" ::: "memory");
      __builtin_amdgcn_s_barrier();
      __builtin_amdgcn_sched_barrier(0);
    }
  }

  // normalize + store: osum[r] matches o0[r]/o1[r] row-for-row
  bf16* obase = att + ((size_t)b * S + q0) * U + h * DH + l31;
#pragma unroll
  for (int r = 0; r < 16; ++r) {
    const int row = (r & 3) + 8 * (r >> 2) + 4 * hi8;
    const float lr = 1.f / osum[r];
    obase[(size_t)row * U]      = (bf16)(o0[r] * lr);
    obase[(size_t)row * U + 32] = (bf16)(o1[r] * lr);
  }
}

// ---------- epilogue: x = relu(att + vres); LayerNorm(x)*gamma + beta ----------
__global__ __launch_bounds__(256) void ln_kernel(
    const bf16* __restrict__ att, const bf16* __restrict__ vres,
    const float* __restrict__ gamma, const float* __restrict__ beta,
    float* __restrict__ out) {
  const int row = blockIdx.x;
  const int t = threadIdx.x;
  const bf16* ar = att + (size_t)row * U;
  const bf16* vr = vres + (size_t)row * U;
  const bf16x4 av = *reinterpret_cast<const bf16x4*>(ar + t * 4);
  const bf16x4 vv = *reinterpret_cast<const bf16x4*>(vr + t * 4);
  float x[4];
  float sum = 0.f, sq = 0.f;
#pragma unroll
  for (int i = 0; i < 4; ++i) {
    x[i] = fmaxf((float)av[i] + (float)vv[i], 0.f);
    sum += x[i];
    sq += x[i] * x[i];
  }
#pragma unroll
  for (int mm = 1; mm < 64; mm <<= 1) {
    sum += __shfl_xor(sum, mm);
    sq  += __shfl_xor(sq, mm);
  }
  __shared__ float s1[4], s2[4];
  if ((t & 63) == 0) { s1[t >> 6] = sum; s2[t >> 6] = sq; }
  __syncthreads();
  sum = s1[0] + s1[1] + s1[2] + s1[3];
  sq  = s2[0] + s2[1] + s2[2] + s2[3];
  const float mean = sum * (1.f / U);
  float var = sq * (1.f / U) - mean * mean;
  var = fmaxf(var, 0.f);
  const float inv = rsqrtf(var + 1e-8f);
#pragma unroll
  for (int i = 0; i < 4; ++i) {
    const int c = t * 4 + i;
    out[(size_t)row * U + c] = gamma[c] * ((x[i] - mean) * inv) + beta[c];
  }
}

extern "C" void kernel_launch(void* const* d_in, const int* in_sizes, int n_in,
                              void* d_out, int out_size, void* d_ws, size_t ws_size,
                              hipStream_t stream) {
  const float* queries = (const float*)d_in[0];
  const float* keys    = (const float*)d_in[1];
  const float* values  = (const float*)d_in[2];
  const float* Wq = (const float*)d_in[3];
  const float* bq = (const float*)d_in[4];
  const float* Wk = (const float*)d_in[5];
  const float* bk = (const float*)d_in[6];
  const float* Wv = (const float*)d_in[7];
  const float* bv = (const float*)d_in[8];
  const float* Wr = (const float*)d_in[9];
  const float* br = (const float*)d_in[10];
  const float* gamma = (const float*)d_in[11];
  const float* beta  = (const float*)d_in[12];
  float* out = (float*)d_out;

  char* ws = (char*)d_ws;
  const size_t MB = 1024 * 1024;
  bf16* wqt  = (bf16*)(ws + 0 * MB);
  bf16* wkt  = (bf16*)(ws + 2 * MB);
  bf16* wvt  = (bf16*)(ws + 4 * MB);
  bf16* wrt  = (bf16*)(ws + 6 * MB);
  bf16* Qcvt = (bf16*)(ws + 8 * MB);    // dead after gemm -> attb aliases
  bf16* Kcvt = (bf16*)(ws + 24 * MB);   // dead after gemm -> Rb aliases (Rb written by gemm z=3)
  bf16* Vcvt = (bf16*)(ws + 40 * MB);
  bf16* Qb   = (bf16*)(ws + 56 * MB);
  bf16* Kp   = (bf16*)(ws + 72 * MB);
  bf16* Vp   = (bf16*)(ws + 88 * MB);   // total 104 MB
  bf16* attb = Qcvt;
  bf16* Rb   = Kcvt;

  prep_kernel<<<dim3(16384), 256, 0, stream>>>(
      queries, keys, values, Qcvt, Kcvt, Vcvt,
      Wq, Wk, Wv, Wr, wqt, wkt, wvt, wrt);
  gemm4_kernel<<<dim3(2048), 256, 0, stream>>>(
      Qcvt, Kcvt, Vcvt, wqt, wkt, wvt, wrt, bq, bk, bv, br, Qb, Kp, Vp, Rb);
  attn_kernel<<<dim3(1024), 256, 0, stream>>>(Qb, Kp, Vp, attb);
  ln_kernel<<<dim3(MTOT), 256, 0, stream>>>(attb, Rb, gamma, beta, out);
}

// Round 16
// 210.248 us; speedup vs baseline: 1.1065x; 1.1065x over previous
//
#include <hip/hip_runtime.h>

constexpr int B = 4, S = 2048, U = 1024, H = 16, DH = 64;
constexpr int MTOT = B * S;
constexpr int NT = S / 64;   // 32 key-tiles of 64

using bf16   = __bf16;
using f32x4  = __attribute__((ext_vector_type(4))) float;
using f32x16 = __attribute__((ext_vector_type(16))) float;
using bf16x8 = __attribute__((ext_vector_type(8))) bf16;
using bf16x4 = __attribute__((ext_vector_type(4))) bf16;
using u32x4  = __attribute__((ext_vector_type(4))) unsigned int;

__device__ __forceinline__ void gload16(const bf16* g, bf16* l) {
  __builtin_amdgcn_global_load_lds(
      (const __attribute__((address_space(1))) unsigned int*)g,
      (__attribute__((address_space(3))) unsigned int*)l, 16, 0, 0);
}

__device__ __forceinline__ float fexp2(float x) {
#if __has_builtin(__builtin_amdgcn_exp2f)
  return __builtin_amdgcn_exp2f(x);
#else
  return __expf(x * 0.6931471805599453f);
#endif
}

__device__ __forceinline__ f32x16 mfma32(bf16x8 a, bf16x8 b, f32x16 c) {
  return __builtin_amdgcn_mfma_f32_32x32x16_bf16(a, b, c, 0, 0, 0);
}

__device__ __forceinline__ unsigned packbf(float a, float b) {
  union { bf16 h; unsigned short s; } ua, ub;
  ua.h = (bf16)a; ub.h = (bf16)b;
  return ((unsigned)ub.s << 16) | (unsigned)ua.s;
}

// packed K layout: Kp[bh][t][tt][ks][ln][8] = K[s = t*64+tt*32+(ln&31)][h*64 + ks*16+(ln>>5)*8+j]
__device__ __forceinline__ size_t kpack_off(int M_, int col) {
  const int b = M_ >> 11, s = M_ & 2047;
  const int h = col >> 6, d = col & 63;
  const int bh = b * 16 + h;
  const int t = s >> 6, r64 = s & 63;
  const int tt = r64 >> 5, l31 = r64 & 31;
  const int ks = d >> 4, hi = (d >> 3) & 1, j = d & 7;
  const int ln = l31 + (hi << 5);
  return ((size_t)(bh * 32 + t) << 12) + (tt << 11) + (ks << 9) + (ln << 3) + j;
}

// packed V layout: Vp[bh][t][dt][ks][ln][8] = V[s = t*64+ks*16+(ln>>5)*8+j][h*64 + dt*32+(ln&31)]
__device__ __forceinline__ size_t vpack_off(int M_, int col) {
  const int b = M_ >> 11, s = M_ & 2047;
  const int h = col >> 6, d = col & 63;
  const int bh = b * 16 + h;
  const int j = s & 7, hi = (s >> 3) & 1, ks = (s >> 4) & 3, t = s >> 6;
  const int dt = d >> 5, l31 = d & 31;
  const int ln = l31 + (hi << 5);
  return ((size_t)(bh * 32 + t) << 12) + (dt << 11) + (ks << 9) + (ln << 3) + j;
}

// ---------- prep: fused {fp32->bf16 convert of q,k,v} + {4x weight transpose+convert} ----------
__global__ __launch_bounds__(256) void prep_kernel(
    const float* __restrict__ xq, const float* __restrict__ xk, const float* __restrict__ xv,
    bf16* __restrict__ oq, bf16* __restrict__ ok, bf16* __restrict__ ov,
    const float* __restrict__ w0, const float* __restrict__ w1,
    const float* __restrict__ w2, const float* __restrict__ w3,
    bf16* __restrict__ t0, bf16* __restrict__ t1,
    bf16* __restrict__ t2, bf16* __restrict__ t3) {
  __shared__ float tile[32][33];
  const int bid = blockIdx.x;
  const int t = threadIdx.x;
  if (bid < 12288) {
    const int z = bid >> 12, idx = bid & 4095;
    const float* x = z == 0 ? xq : z == 1 ? xk : xv;
    bf16* o       = z == 0 ? oq : z == 1 ? ok : ov;
    const size_t i = ((size_t)idx * 256 + t) * 8;
    const float4 v0 = *reinterpret_cast<const float4*>(x + i);
    const float4 v1 = *reinterpret_cast<const float4*>(x + i + 4);
    bf16x8 r;
    r[0] = (bf16)v0.x; r[1] = (bf16)v0.y; r[2] = (bf16)v0.z; r[3] = (bf16)v0.w;
    r[4] = (bf16)v1.x; r[5] = (bf16)v1.y; r[6] = (bf16)v1.z; r[7] = (bf16)v1.w;
    *reinterpret_cast<bf16x8*>(o + i) = r;
  } else {
    const int wb = bid - 12288;
    const int z = wb >> 10, ti = wb & 1023;
    const float* W = z == 0 ? w0 : z == 1 ? w1 : z == 2 ? w2 : w3;
    bf16* Wt       = z == 0 ? t0 : z == 1 ? t1 : z == 2 ? t2 : t3;
    const int k0 = (ti & 31) * 32, n0 = (ti >> 5) * 32;
    const int tx = t & 31, ty = t >> 5;
    for (int i = ty; i < 32; i += 8) tile[i][tx] = W[(size_t)(k0 + i) * U + n0 + tx];
    __syncthreads();
    for (int i = ty; i < 32; i += 8) Wt[(size_t)(n0 + i) * U + k0 + tx] = (bf16)tile[tx][i];
  }
}

// ---------- fused 4-GEMM: out = relu(A @ Wt^T + b) ----------
// Round-12/14-verified optimum for this structure class: 128^2 tile, 4 waves 2x2,
// BK=64 (16 barrier pairs), two-sided row-XOR slot swizzle, XCD-chunk swizzle.
// (Pipelining variants r7/r10/r11/r15 all regressed -> keep the simple 2-barrier loop.)
__global__ __launch_bounds__(256) void gemm4_kernel(
    const bf16* __restrict__ Qc, const bf16* __restrict__ Kc, const bf16* __restrict__ Vc,
    const bf16* __restrict__ wqt, const bf16* __restrict__ wkt,
    const bf16* __restrict__ wvt, const bf16* __restrict__ wrt,
    const float* __restrict__ bq, const float* __restrict__ bk,
    const float* __restrict__ bv, const float* __restrict__ br,
    bf16* __restrict__ oq, bf16* __restrict__ okp,
    bf16* __restrict__ ovp, bf16* __restrict__ orr) {
  const int bid = blockIdx.x;
  const int wg = (bid & 7) * 256 + (bid >> 3);   // bijective: 2048 % 8 == 0
  const int z = wg >> 9, rem = wg & 511;
  const int bm = (rem >> 3) * 128, bn = (rem & 7) * 128;

  const bf16* A     = z == 0 ? Qc : z == 1 ? Kc : Vc;   // z==2,3 read Vcvt
  const bf16* Wt    = z == 0 ? wqt : z == 1 ? wkt : z == 2 ? wvt : wrt;
  const float* bias = z == 0 ? bq : z == 1 ? bk : z == 2 ? bv : br;

  const int t = threadIdx.x, lane = t & 63, wid = t >> 6;
  const int wr = wid >> 1, wc = wid & 1;
  const int lm = lane & 15, hi = lane >> 4;

  __shared__ __align__(16) bf16 As[128][64];   // 16KB
  __shared__ __align__(16) bf16 Bs[128][64];   // 16KB

  f32x4 acc[4][4];
#pragma unroll
  for (int i = 0; i < 4; ++i)
#pragma unroll
    for (int j = 0; j < 4; ++j) acc[i][j] = f32x4{0.f, 0.f, 0.f, 0.f};

  const int lr = lane >> 3;
  const int scol = ((lane & 7) ^ lr) * 8;
  const bf16* ga = A  + (size_t)(bm + wid * 32 + lr) * U + scol;
  const bf16* gb = Wt + (size_t)(bn + wid * 32 + lr) * U + scol;

  for (int k0 = 0; k0 < U; k0 += 64) {
    __syncthreads();
#pragma unroll
    for (int p = 0; p < 4; ++p) {
      gload16(ga + (size_t)(p * 8) * U + k0, &As[wid * 32 + p * 8][0]);
      gload16(gb + (size_t)(p * 8) * U + k0, &Bs[wid * 32 + p * 8][0]);
    }
    __syncthreads();

#pragma unroll
    for (int ksub = 0; ksub < 2; ++ksub) {
      const int so = (((ksub * 4 + hi) ^ (lm & 7)) * 16);   // byte offset in 128B row
      bf16x8 a[4], bb[4];
#pragma unroll
      for (int mi = 0; mi < 4; ++mi)
        a[mi] = *reinterpret_cast<const bf16x8*>(
            reinterpret_cast<const char*>(&As[wr * 64 + mi * 16 + lm][0]) + so);
#pragma unroll
      for (int ni = 0; ni < 4; ++ni)
        bb[ni] = *reinterpret_cast<const bf16x8*>(
            reinterpret_cast<const char*>(&Bs[wc * 64 + ni * 16 + lm][0]) + so);
#pragma unroll
      for (int mi = 0; mi < 4; ++mi)
#pragma unroll
        for (int ni = 0; ni < 4; ++ni)
          acc[mi][ni] = __builtin_amdgcn_mfma_f32_16x16x32_bf16(a[mi], bb[ni], acc[mi][ni], 0, 0, 0);
    }
  }

  const int mb = bm + wr * 64 + hi * 4;
  const int nb = bn + wc * 64 + lm;
  if (z == 1) {
#pragma unroll
    for (int ni = 0; ni < 4; ++ni) {
      const float bv_ = bias[nb + ni * 16];
#pragma unroll
      for (int mi = 0; mi < 4; ++mi)
#pragma unroll
        for (int r = 0; r < 4; ++r) {
          const float vv = fmaxf(acc[mi][ni][r] + bv_, 0.f);
          okp[kpack_off(mb + mi * 16 + r, nb + ni * 16)] = (bf16)vv;
        }
    }
  } else if (z == 2) {
#pragma unroll
    for (int ni = 0; ni < 4; ++ni) {
      const float bv_ = bias[nb + ni * 16];
#pragma unroll
      for (int mi = 0; mi < 4; ++mi)
#pragma unroll
        for (int r = 0; r < 4; ++r) {
          const float vv = fmaxf(acc[mi][ni][r] + bv_, 0.f);
          ovp[vpack_off(mb + mi * 16 + r, nb + ni * 16)] = (bf16)vv;
        }
    }
  } else {
    bf16* out = z == 0 ? oq : orr;
#pragma unroll
    for (int ni = 0; ni < 4; ++ni) {
      const float bv_ = bias[nb + ni * 16];
#pragma unroll
      for (int mi = 0; mi < 4; ++mi)
#pragma unroll
        for (int r = 0; r < 4; ++r) {
          const float vv = fmaxf(acc[mi][ni][r] + bv_, 0.f);
          out[(size_t)(mb + mi * 16 + r) * U + nb + ni * 16] = (bf16)vv;
        }
    }
  }
}

// ---------- flash attention: packed K/V, 2-buffer LDS pipeline (32KB) ----------
// 4 waves x 32 q-rows. Swapped QK^T (32x32x16); no-max softmax (r13/r14-verified);
// denominator via ones-MFMA; half-exchange via v_permlane32_swap_b32.
__global__ __launch_bounds__(256, 2) void attn_kernel(
    const bf16* __restrict__ Q, const bf16* __restrict__ Kp,
    const bf16* __restrict__ Vp, bf16* __restrict__ att) {
  const int bid = blockIdx.x;
  const int swz = (bid & 7) * 128 + (bid >> 3);     // 8 bh per XCD
  const int bh = swz >> 4, qx = swz & 15;
  const int b = bh >> 4, h = bh & 15;
  const int tid = threadIdx.x;
  const int w = tid >> 6, lane = tid & 63;
  const int l31 = lane & 31, hi8 = lane >> 5;
  const int q0 = qx * 128 + w * 32;

  __shared__ __align__(16) bf16 kv[2][8192];   // [0..4095]=K tile, [4096..8191]=V tile

  const float qscale = 0.18033688011111606f;  // log2(e)/sqrt(DH)

  // Q fragments (B operand: col = q = l31, contraction = dh)
  const bf16* qbase = Q + ((size_t)b * S + q0 + l31) * U + h * DH + hi8 * 8;
  bf16x8 qf[4];
#pragma unroll
  for (int ks = 0; ks < 4; ++ks) {
    bf16x8 v = *reinterpret_cast<const bf16x8*>(qbase + ks * 16);
#pragma unroll
    for (int j = 0; j < 8; ++j) v[j] = (bf16)((float)v[j] * qscale);
    qf[ks] = v;
  }

  bf16x8 onesf;
#pragma unroll
  for (int j = 0; j < 8; ++j) onesf[j] = (bf16)1.f;

  f32x16 o0 = (f32x16)0.f, o1 = (f32x16)0.f, osum = (f32x16)0.f;

  const bf16* kpb = Kp + (size_t)bh * 32 * 4096;
  const bf16* vpb = Vp + (size_t)bh * 32 * 4096;

  auto stagekv = [&](int buf, int t) {
    const size_t toff = (size_t)t * 4096;
    gload16(kpb + toff + tid * 8,        &kv[buf][tid * 8]);
    gload16(kpb + toff + 2048 + tid * 8, &kv[buf][2048 + tid * 8]);
    gload16(vpb + toff + tid * 8,        &kv[buf][4096 + tid * 8]);
    gload16(vpb + toff + 2048 + tid * 8, &kv[buf][6144 + tid * 8]);
  };

  stagekv(0, 0);
  asm volatile("s_waitcnt vmcnt(0)" ::: "memory");
  __builtin_amdgcn_s_barrier();
  __builtin_amdgcn_sched_barrier(0);

  for (int t = 0; t < NT; ++t) {
    const int cur = t & 1;
    if (t + 1 < NT) stagekv(cur ^ 1, t + 1);

    bf16x8 kf[2][4];
#pragma unroll
    for (int tt = 0; tt < 2; ++tt)
#pragma unroll
      for (int ks = 0; ks < 4; ++ks)
        kf[tt][ks] = *reinterpret_cast<const bf16x8*>(&kv[cur][(tt * 4 + ks) * 512 + lane * 8]);

    // S^T = K Q^T : rows = k, cols = q (l31)
    f32x16 s0 = (f32x16)0.f, s1 = (f32x16)0.f;
    __builtin_amdgcn_s_setprio(1);
#pragma unroll
    for (int ks = 0; ks < 4; ++ks) {
      s0 = mfma32(kf[0][ks], qf[ks], s0);
      s1 = mfma32(kf[1][ks], qf[ks], s1);
    }
    __builtin_amdgcn_s_setprio(0);

    bf16x8 vf[2][4];
#pragma unroll
    for (int dt = 0; dt < 2; ++dt)
#pragma unroll
      for (int ks = 0; ks < 4; ++ks)
        vf[dt][ks] = *reinterpret_cast<const bf16x8*>(&kv[cur][4096 + (dt * 4 + ks) * 512 + lane * 8]);

    // P = exp2(s) lane-local; pack to bf16 pairs (no max subtraction needed)
    unsigned wpk[16];
#pragma unroll
    for (int i = 0; i < 8; ++i) {
      wpk[i]     = packbf(fexp2(s0[2 * i]), fexp2(s0[2 * i + 1]));
      wpk[8 + i] = packbf(fexp2(s1[2 * i]), fexp2(s1[2 * i + 1]));
    }

    // half-exchange via permlane32_swap
    u32x4 fw[4];
#pragma unroll
    for (int fi = 0; fi < 4; ++fi) {
      unsigned a0 = wpk[fi * 4 + 0], b0 = wpk[fi * 4 + 2];
      unsigned a1 = wpk[fi * 4 + 1], b1 = wpk[fi * 4 + 3];
      asm("v_permlane32_swap_b32 %0, %1" : "+v"(a0), "+v"(b0));
      asm("v_permlane32_swap_b32 %0, %1" : "+v"(a1), "+v"(b1));
      fw[fi] = u32x4{a0, a1, b0, b1};
    }

    // O += P V ; row-sum += P * ones  (denominator in the matrix pipe, same C layout)
    __builtin_amdgcn_s_setprio(1);
#pragma unroll
    for (int ks = 0; ks < 4; ++ks) {
      const bf16x8 pf = __builtin_bit_cast(bf16x8, fw[ks]);
      o0   = mfma32(pf, vf[0][ks], o0);
      o1   = mfma32(pf, vf[1][ks], o1);
      osum = mfma32(pf, onesf, osum);
    }
    __builtin_amdgcn_s_setprio(0);

    if (t + 1 < NT) {
      asm volatile("s_waitcnt vmcnt(0)" ::: "memory");
      __builtin_amdgcn_s_barrier();
      __builtin_amdgcn_sched_barrier(0);
    }
  }

  // normalize + store: osum[r] matches o0[r]/o1[r] row-for-row
  bf16* obase = att + ((size_t)b * S + q0) * U + h * DH + l31;
#pragma unroll
  for (int r = 0; r < 16; ++r) {
    const int row = (r & 3) + 8 * (r >> 2) + 4 * hi8;
    const float lr = 1.f / osum[r];
    obase[(size_t)row * U]      = (bf16)(o0[r] * lr);
    obase[(size_t)row * U + 32] = (bf16)(o1[r] * lr);
  }
}

// ---------- epilogue: x = relu(att + vres); LayerNorm(x)*gamma + beta ----------
// One WAVE per row (no LDS, no __syncthreads), 4 rows per 256-thread block.
// Lane owns 16 columns: 2x bf16x8 from att + 2x from vres; 6-step shfl_xor reduce.
__global__ __launch_bounds__(256) void ln_kernel(
    const bf16* __restrict__ att, const bf16* __restrict__ vres,
    const float* __restrict__ gamma, const float* __restrict__ beta,
    float* __restrict__ out) {
  const int w = threadIdx.x >> 6, lane = threadIdx.x & 63;
  const int row = blockIdx.x * 4 + w;
  const int c0 = lane * 16;
  const bf16* ar = att  + (size_t)row * U + c0;
  const bf16* vr = vres + (size_t)row * U + c0;

  const bf16x8 a0 = *reinterpret_cast<const bf16x8*>(ar);
  const bf16x8 a1 = *reinterpret_cast<const bf16x8*>(ar + 8);
  const bf16x8 v0 = *reinterpret_cast<const bf16x8*>(vr);
  const bf16x8 v1 = *reinterpret_cast<const bf16x8*>(vr + 8);

  float x[16];
  float sum = 0.f, sq = 0.f;
#pragma unroll
  for (int i = 0; i < 8; ++i) {
    x[i]     = fmaxf((float)a0[i] + (float)v0[i], 0.f);
    x[8 + i] = fmaxf((float)a1[i] + (float)v1[i], 0.f);
  }
#pragma unroll
  for (int i = 0; i < 16; ++i) { sum += x[i]; sq += x[i] * x[i]; }
#pragma unroll
  for (int mm = 1; mm < 64; mm <<= 1) {
    sum += __shfl_xor(sum, mm);
    sq  += __shfl_xor(sq, mm);
  }
  const float mean = sum * (1.f / U);
  float var = sq * (1.f / U) - mean * mean;
  var = fmaxf(var, 0.f);
  const float inv = rsqrtf(var + 1e-8f);

  float* orow = out + (size_t)row * U + c0;
#pragma unroll
  for (int j = 0; j < 4; ++j) {
    const float4 g = *reinterpret_cast<const float4*>(gamma + c0 + j * 4);
    const float4 bt = *reinterpret_cast<const float4*>(beta + c0 + j * 4);
    float4 o;
    o.x = g.x * ((x[j * 4 + 0] - mean) * inv) + bt.x;
    o.y = g.y * ((x[j * 4 + 1] - mean) * inv) + bt.y;
    o.z = g.z * ((x[j * 4 + 2] - mean) * inv) + bt.z;
    o.w = g.w * ((x[j * 4 + 3] - mean) * inv) + bt.w;
    *reinterpret_cast<float4*>(orow + j * 4) = o;
  }
}

extern "C" void kernel_launch(void* const* d_in, const int* in_sizes, int n_in,
                              void* d_out, int out_size, void* d_ws, size_t ws_size,
                              hipStream_t stream) {
  const float* queries = (const float*)d_in[0];
  const float* keys    = (const float*)d_in[1];
  const float* values  = (const float*)d_in[2];
  const float* Wq = (const float*)d_in[3];
  const float* bq = (const float*)d_in[4];
  const float* Wk = (const float*)d_in[5];
  const float* bk = (const float*)d_in[6];
  const float* Wv = (const float*)d_in[7];
  const float* bv = (const float*)d_in[8];
  const float* Wr = (const float*)d_in[9];
  const float* br = (const float*)d_in[10];
  const float* gamma = (const float*)d_in[11];
  const float* beta  = (const float*)d_in[12];
  float* out = (float*)d_out;

  char* ws = (char*)d_ws;
  const size_t MB = 1024 * 1024;
  bf16* wqt  = (bf16*)(ws + 0 * MB);
  bf16* wkt  = (bf16*)(ws + 2 * MB);
  bf16* wvt  = (bf16*)(ws + 4 * MB);
  bf16* wrt  = (bf16*)(ws + 6 * MB);
  bf16* Qcvt = (bf16*)(ws + 8 * MB);    // dead after gemm -> attb aliases
  bf16* Kcvt = (bf16*)(ws + 24 * MB);   // dead after gemm -> Rb aliases (Rb written by gemm z=3)
  bf16* Vcvt = (bf16*)(ws + 40 * MB);
  bf16* Qb   = (bf16*)(ws + 56 * MB);
  bf16* Kp   = (bf16*)(ws + 72 * MB);
  bf16* Vp   = (bf16*)(ws + 88 * MB);   // total 104 MB
  bf16* attb = Qcvt;
  bf16* Rb   = Kcvt;

  prep_kernel<<<dim3(16384), 256, 0, stream>>>(
      queries, keys, values, Qcvt, Kcvt, Vcvt,
      Wq, Wk, Wv, Wr, wqt, wkt, wvt, wrt);
  gemm4_kernel<<<dim3(2048), 256, 0, stream>>>(
      Qcvt, Kcvt, Vcvt, wqt, wkt, wvt, wrt, bq, bk, bv, br, Qb, Kp, Vp, Rb);
  attn_kernel<<<dim3(1024), 256, 0, stream>>>(Qb, Kp, Vp, attb);
  ln_kernel<<<dim3(MTOT / 4), 256, 0, stream>>>(attb, Rb, gamma, beta, out);
}

// Round 17
// 201.543 us; speedup vs baseline: 1.1543x; 1.0432x over previous
//
#include <hip/hip_runtime.h>

constexpr int B = 4, S = 2048, U = 1024, H = 16, DH = 64;
constexpr int MTOT = B * S;
constexpr int NT = S / 64;   // 32 key-tiles of 64

using bf16   = __bf16;
using f32x4  = __attribute__((ext_vector_type(4))) float;
using f32x16 = __attribute__((ext_vector_type(16))) float;
using bf16x8 = __attribute__((ext_vector_type(8))) bf16;
using bf16x4 = __attribute__((ext_vector_type(4))) bf16;
using u32x4  = __attribute__((ext_vector_type(4))) unsigned int;

__device__ __forceinline__ void gload16(const bf16* g, bf16* l) {
  __builtin_amdgcn_global_load_lds(
      (const __attribute__((address_space(1))) unsigned int*)g,
      (__attribute__((address_space(3))) unsigned int*)l, 16, 0, 0);
}

__device__ __forceinline__ float fexp2(float x) {
#if __has_builtin(__builtin_amdgcn_exp2f)
  return __builtin_amdgcn_exp2f(x);
#else
  return __expf(x * 0.6931471805599453f);
#endif
}

__device__ __forceinline__ f32x16 mfma32(bf16x8 a, bf16x8 b, f32x16 c) {
  return __builtin_amdgcn_mfma_f32_32x32x16_bf16(a, b, c, 0, 0, 0);
}

__device__ __forceinline__ unsigned packbf(float a, float b) {
  union { bf16 h; unsigned short s; } ua, ub;
  ua.h = (bf16)a; ub.h = (bf16)b;
  return ((unsigned)ub.s << 16) | (unsigned)ua.s;
}

// packed K layout: Kp[bh][t][tt][ks][ln][8] = K[s = t*64+tt*32+(ln&31)][h*64 + ks*16+(ln>>5)*8+j]
__device__ __forceinline__ size_t kpack_off(int M_, int col) {
  const int b = M_ >> 11, s = M_ & 2047;
  const int h = col >> 6, d = col & 63;
  const int bh = b * 16 + h;
  const int t = s >> 6, r64 = s & 63;
  const int tt = r64 >> 5, l31 = r64 & 31;
  const int ks = d >> 4, hi = (d >> 3) & 1, j = d & 7;
  const int ln = l31 + (hi << 5);
  return ((size_t)(bh * 32 + t) << 12) + (tt << 11) + (ks << 9) + (ln << 3) + j;
}

// packed V layout: Vp[bh][t][dt][ks][ln][8] = V[s = t*64+ks*16+(ln>>5)*8+j][h*64 + dt*32+(ln&31)]
__device__ __forceinline__ size_t vpack_off(int M_, int col) {
  const int b = M_ >> 11, s = M_ & 2047;
  const int h = col >> 6, d = col & 63;
  const int bh = b * 16 + h;
  const int j = s & 7, hi = (s >> 3) & 1, ks = (s >> 4) & 3, t = s >> 6;
  const int dt = d >> 5, l31 = d & 31;
  const int ln = l31 + (hi << 5);
  return ((size_t)(bh * 32 + t) << 12) + (dt << 11) + (ks << 9) + (ln << 3) + j;
}

// ---------- prep: fused {fp32->bf16 convert of q,k,v} + {4x weight transpose+convert} ----------
__global__ __launch_bounds__(256) void prep_kernel(
    const float* __restrict__ xq, const float* __restrict__ xk, const float* __restrict__ xv,
    bf16* __restrict__ oq, bf16* __restrict__ ok, bf16* __restrict__ ov,
    const float* __restrict__ w0, const float* __restrict__ w1,
    const float* __restrict__ w2, const float* __restrict__ w3,
    bf16* __restrict__ t0, bf16* __restrict__ t1,
    bf16* __restrict__ t2, bf16* __restrict__ t3) {
  __shared__ float tile[32][33];
  const int bid = blockIdx.x;
  const int t = threadIdx.x;
  if (bid < 12288) {
    const int z = bid >> 12, idx = bid & 4095;
    const float* x = z == 0 ? xq : z == 1 ? xk : xv;
    bf16* o       = z == 0 ? oq : z == 1 ? ok : ov;
    const size_t i = ((size_t)idx * 256 + t) * 8;
    const float4 v0 = *reinterpret_cast<const float4*>(x + i);
    const float4 v1 = *reinterpret_cast<const float4*>(x + i + 4);
    bf16x8 r;
    r[0] = (bf16)v0.x; r[1] = (bf16)v0.y; r[2] = (bf16)v0.z; r[3] = (bf16)v0.w;
    r[4] = (bf16)v1.x; r[5] = (bf16)v1.y; r[6] = (bf16)v1.z; r[7] = (bf16)v1.w;
    *reinterpret_cast<bf16x8*>(o + i) = r;
  } else {
    const int wb = bid - 12288;
    const int z = wb >> 10, ti = wb & 1023;
    const float* W = z == 0 ? w0 : z == 1 ? w1 : z == 2 ? w2 : w3;
    bf16* Wt       = z == 0 ? t0 : z == 1 ? t1 : z == 2 ? t2 : t3;
    const int k0 = (ti & 31) * 32, n0 = (ti >> 5) * 32;
    const int tx = t & 31, ty = t >> 5;
    for (int i = ty; i < 32; i += 8) tile[i][tx] = W[(size_t)(k0 + i) * U + n0 + tx];
    __syncthreads();
    for (int i = ty; i < 32; i += 8) Wt[(size_t)(n0 + i) * U + k0 + tx] = (bf16)tile[tx][i];
  }
}

// ---------- fused 4-GEMM: out = relu(A @ Wt^T + b) ----------
// 8-phase-style 256x256 template (T3+T4+T5): 8 waves (2M x 4N), BK=64, 128KB LDS
// 2-buffer. Per K-tile: 4 phases, each {stage ONE half-tile of t+1 (2 gload/thread)
// -> compute one mi-quadrant (16 MFMA, setprio)}; ONE vmcnt(0)+barrier per K-tile,
// newest stage issued a full phase before the wait -> L2 latency hidden.
// r12-verified slot swizzle: LDS[r][s] = data[r][s ^ (r&7)]; read slot (ks*4+hi)^(lm&7).
__global__ __launch_bounds__(512, 2) void gemm4_kernel(
    const bf16* __restrict__ Qc, const bf16* __restrict__ Kc, const bf16* __restrict__ Vc,
    const bf16* __restrict__ wqt, const bf16* __restrict__ wkt,
    const bf16* __restrict__ wvt, const bf16* __restrict__ wrt,
    const float* __restrict__ bq, const float* __restrict__ bk,
    const float* __restrict__ bv, const float* __restrict__ br,
    bf16* __restrict__ oq, bf16* __restrict__ okp,
    bf16* __restrict__ ovp, bf16* __restrict__ orr) {
  const int bid = blockIdx.x;
  const int wg = (bid & 7) * 64 + (bid >> 3);   // bijective: 512 % 8 == 0
  const int z = wg >> 7, rem = wg & 127;
  const int bm = (rem >> 2) * 256, bn = (rem & 3) * 256;

  const bf16* A     = z == 0 ? Qc : z == 1 ? Kc : Vc;   // z==2,3 read Vcvt
  const bf16* Wt    = z == 0 ? wqt : z == 1 ? wkt : z == 2 ? wvt : wrt;
  const float* bias = z == 0 ? bq : z == 1 ? bk : z == 2 ? bv : br;

  const int tid = threadIdx.x, lane = tid & 63, w = tid >> 6;
  const int wr = w >> 2, wcn = w & 3;
  const int lm = lane & 15, hi = lane >> 4;

  // 128KB: [buf][ A 16384 elems | B 16384 elems ]
  __shared__ __align__(16) bf16 smem[65536];

  f32x4 acc[8][4];
#pragma unroll
  for (int i = 0; i < 8; ++i)
#pragma unroll
    for (int j = 0; j < 4; ++j) acc[i][j] = f32x4{0.f, 0.f, 0.f, 0.f};

  // staging: 512 threads, rows tid>>3 (0..63), slot tid&7; source col pre-swizzled.
  const int srow = tid >> 3, sslot = tid & 7;
  const int scol = (sslot ^ (srow & 7)) * 8;
  const bf16* gA = A  + (size_t)(bm + srow) * U + scol;
  const bf16* gB = Wt + (size_t)(bn + srow) * U + scol;

  auto stageA = [&](int buf, int half, int k0) {
    bf16* l = smem + buf * 32768 + (half * 128 + srow) * 64 + sslot * 8;
    gload16(gA + (size_t)(half * 128) * U + k0, l);
    gload16(gA + (size_t)(half * 128 + 64) * U + k0, l + 64 * 64);
  };
  auto stageB = [&](int buf, int half, int k0) {
    bf16* l = smem + buf * 32768 + 16384 + (half * 128 + srow) * 64 + sslot * 8;
    gload16(gB + (size_t)(half * 128) * U + k0, l);
    gload16(gB + (size_t)(half * 128 + 64) * U + k0, l + 64 * 64);
  };

  auto loadA = [&](int buf, int mi, int ks) {
    const int row = wr * 128 + mi * 16 + lm;
    const int slot = (ks * 4 + hi) ^ (lm & 7);
    return *reinterpret_cast<const bf16x8*>(smem + buf * 32768 + row * 64 + slot * 8);
  };
  auto loadB = [&](int buf, int ni, int ks) {
    const int row = wcn * 64 + ni * 16 + lm;
    const int slot = (ks * 4 + hi) ^ (lm & 7);
    return *reinterpret_cast<const bf16x8*>(smem + buf * 32768 + 16384 + row * 64 + slot * 8);
  };

  // prologue: K-tile 0 fully staged
  stageA(0, 0, 0); stageA(0, 1, 0); stageB(0, 0, 0); stageB(0, 1, 0);
  asm volatile("s_waitcnt vmcnt(0)" ::: "memory");
  __builtin_amdgcn_s_barrier();
  __builtin_amdgcn_sched_barrier(0);

  for (int t = 0; t < 16; ++t) {
    const int buf = t & 1, nbf = buf ^ 1;
    const int k1 = (t + 1) * 64;
    const bool pre = (t + 1) < 16;

    bf16x8 bfr[4][2];

    // ---- phase 0: stage A-half0(t+1); B-frags + quadrant mi {0,1}
    if (pre) stageA(nbf, 0, k1);
#pragma unroll
    for (int ni = 0; ni < 4; ++ni) {
      bfr[ni][0] = loadB(buf, ni, 0);
      bfr[ni][1] = loadB(buf, ni, 1);
    }
    {
      bf16x8 a00 = loadA(buf, 0, 0), a01 = loadA(buf, 0, 1);
      bf16x8 a10 = loadA(buf, 1, 0), a11 = loadA(buf, 1, 1);
      __builtin_amdgcn_s_setprio(1);
#pragma unroll
      for (int ni = 0; ni < 4; ++ni) {
        acc[0][ni] = __builtin_amdgcn_mfma_f32_16x16x32_bf16(a00, bfr[ni][0], acc[0][ni], 0, 0, 0);
        acc[0][ni] = __builtin_amdgcn_mfma_f32_16x16x32_bf16(a01, bfr[ni][1], acc[0][ni], 0, 0, 0);
        acc[1][ni] = __builtin_amdgcn_mfma_f32_16x16x32_bf16(a10, bfr[ni][0], acc[1][ni], 0, 0, 0);
        acc[1][ni] = __builtin_amdgcn_mfma_f32_16x16x32_bf16(a11, bfr[ni][1], acc[1][ni], 0, 0, 0);
      }
      __builtin_amdgcn_s_setprio(0);
    }
    // ---- phase 1: stage A-half1(t+1); quadrant mi {2,3}
    if (pre) stageA(nbf, 1, k1);
    {
      bf16x8 a00 = loadA(buf, 2, 0), a01 = loadA(buf, 2, 1);
      bf16x8 a10 = loadA(buf, 3, 0), a11 = loadA(buf, 3, 1);
      __builtin_amdgcn_s_setprio(1);
#pragma unroll
      for (int ni = 0; ni < 4; ++ni) {
        acc[2][ni] = __builtin_amdgcn_mfma_f32_16x16x32_bf16(a00, bfr[ni][0], acc[2][ni], 0, 0, 0);
        acc[2][ni] = __builtin_amdgcn_mfma_f32_16x16x32_bf16(a01, bfr[ni][1], acc[2][ni], 0, 0, 0);
        acc[3][ni] = __builtin_amdgcn_mfma_f32_16x16x32_bf16(a10, bfr[ni][0], acc[3][ni], 0, 0, 0);
        acc[3][ni] = __builtin_amdgcn_mfma_f32_16x16x32_bf16(a11, bfr[ni][1], acc[3][ni], 0, 0, 0);
      }
      __builtin_amdgcn_s_setprio(0);
    }
    // ---- phase 2: stage B-half0(t+1); quadrant mi {4,5}
    if (pre) stageB(nbf, 0, k1);
    {
      bf16x8 a00 = loadA(buf, 4, 0), a01 = loadA(buf, 4, 1);
      bf16x8 a10 = loadA(buf, 5, 0), a11 = loadA(buf, 5, 1);
      __builtin_amdgcn_s_setprio(1);
#pragma unroll
      for (int ni = 0; ni < 4; ++ni) {
        acc[4][ni] = __builtin_amdgcn_mfma_f32_16x16x32_bf16(a00, bfr[ni][0], acc[4][ni], 0, 0, 0);
        acc[4][ni] = __builtin_amdgcn_mfma_f32_16x16x32_bf16(a01, bfr[ni][1], acc[4][ni], 0, 0, 0);
        acc[5][ni] = __builtin_amdgcn_mfma_f32_16x16x32_bf16(a10, bfr[ni][0], acc[5][ni], 0, 0, 0);
        acc[5][ni] = __builtin_amdgcn_mfma_f32_16x16x32_bf16(a11, bfr[ni][1], acc[5][ni], 0, 0, 0);
      }
      __builtin_amdgcn_s_setprio(0);
    }
    // ---- phase 3: stage B-half1(t+1); quadrant mi {6,7}
    if (pre) stageB(nbf, 1, k1);
    {
      bf16x8 a00 = loadA(buf, 6, 0), a01 = loadA(buf, 6, 1);
      bf16x8 a10 = loadA(buf, 7, 0), a11 = loadA(buf, 7, 1);
      __builtin_amdgcn_s_setprio(1);
#pragma unroll
      for (int ni = 0; ni < 4; ++ni) {
        acc[6][ni] = __builtin_amdgcn_mfma_f32_16x16x32_bf16(a00, bfr[ni][0], acc[6][ni], 0, 0, 0);
        acc[6][ni] = __builtin_amdgcn_mfma_f32_16x16x32_bf16(a01, bfr[ni][1], acc[6][ni], 0, 0, 0);
        acc[7][ni] = __builtin_amdgcn_mfma_f32_16x16x32_bf16(a10, bfr[ni][0], acc[7][ni], 0, 0, 0);
        acc[7][ni] = __builtin_amdgcn_mfma_f32_16x16x32_bf16(a11, bfr[ni][1], acc[7][ni], 0, 0, 0);
      }
      __builtin_amdgcn_s_setprio(0);
    }

    if (pre) {
      // own t+1 loads: newest issued a full phase (~300cy) ago -> near-free drain;
      // barrier publishes buf^1 and frees buf for staging at t+1.
      asm volatile("s_waitcnt vmcnt(0)" ::: "memory");
      __builtin_amdgcn_s_barrier();
      __builtin_amdgcn_sched_barrier(0);
    }
  }

  const int mb = bm + wr * 128 + hi * 4;
  const int nb = bn + wcn * 64 + lm;
  if (z == 1) {
#pragma unroll
    for (int ni = 0; ni < 4; ++ni) {
      const float bv_ = bias[nb + ni * 16];
#pragma unroll
      for (int mi = 0; mi < 8; ++mi)
#pragma unroll
        for (int r = 0; r < 4; ++r) {
          const float vv = fmaxf(acc[mi][ni][r] + bv_, 0.f);
          okp[kpack_off(mb + mi * 16 + r, nb + ni * 16)] = (bf16)vv;
        }
    }
  } else if (z == 2) {
#pragma unroll
    for (int ni = 0; ni < 4; ++ni) {
      const float bv_ = bias[nb + ni * 16];
#pragma unroll
      for (int mi = 0; mi < 8; ++mi)
#pragma unroll
        for (int r = 0; r < 4; ++r) {
          const float vv = fmaxf(acc[mi][ni][r] + bv_, 0.f);
          ovp[vpack_off(mb + mi * 16 + r, nb + ni * 16)] = (bf16)vv;
        }
    }
  } else {
    bf16* out = z == 0 ? oq : orr;
#pragma unroll
    for (int ni = 0; ni < 4; ++ni) {
      const float bv_ = bias[nb + ni * 16];
#pragma unroll
      for (int mi = 0; mi < 8; ++mi)
#pragma unroll
        for (int r = 0; r < 4; ++r) {
          const float vv = fmaxf(acc[mi][ni][r] + bv_, 0.f);
          out[(size_t)(mb + mi * 16 + r) * U + nb + ni * 16] = (bf16)vv;
        }
    }
  }
}

// ---------- flash attention: packed K/V, 2-buffer LDS pipeline (32KB) ----------
// 4 waves x 32 q-rows. Swapped QK^T (32x32x16); no-max softmax (r13/r14-verified);
// denominator via ones-MFMA; half-exchange via v_permlane32_swap_b32.
__global__ __launch_bounds__(256, 2) void attn_kernel(
    const bf16* __restrict__ Q, const bf16* __restrict__ Kp,
    const bf16* __restrict__ Vp, bf16* __restrict__ att) {
  const int bid = blockIdx.x;
  const int swz = (bid & 7) * 128 + (bid >> 3);     // 8 bh per XCD
  const int bh = swz >> 4, qx = swz & 15;
  const int b = bh >> 4, h = bh & 15;
  const int tid = threadIdx.x;
  const int w = tid >> 6, lane = tid & 63;
  const int l31 = lane & 31, hi8 = lane >> 5;
  const int q0 = qx * 128 + w * 32;

  __shared__ __align__(16) bf16 kv[2][8192];   // [0..4095]=K tile, [4096..8191]=V tile

  const float qscale = 0.18033688011111606f;  // log2(e)/sqrt(DH)

  // Q fragments (B operand: col = q = l31, contraction = dh)
  const bf16* qbase = Q + ((size_t)b * S + q0 + l31) * U + h * DH + hi8 * 8;
  bf16x8 qf[4];
#pragma unroll
  for (int ks = 0; ks < 4; ++ks) {
    bf16x8 v = *reinterpret_cast<const bf16x8*>(qbase + ks * 16);
#pragma unroll
    for (int j = 0; j < 8; ++j) v[j] = (bf16)((float)v[j] * qscale);
    qf[ks] = v;
  }

  bf16x8 onesf;
#pragma unroll
  for (int j = 0; j < 8; ++j) onesf[j] = (bf16)1.f;

  f32x16 o0 = (f32x16)0.f, o1 = (f32x16)0.f, osum = (f32x16)0.f;

  const bf16* kpb = Kp + (size_t)bh * 32 * 4096;
  const bf16* vpb = Vp + (size_t)bh * 32 * 4096;

  auto stagekv = [&](int buf, int t) {
    const size_t toff = (size_t)t * 4096;
    gload16(kpb + toff + tid * 8,        &kv[buf][tid * 8]);
    gload16(kpb + toff + 2048 + tid * 8, &kv[buf][2048 + tid * 8]);
    gload16(vpb + toff + tid * 8,        &kv[buf][4096 + tid * 8]);
    gload16(vpb + toff + 2048 + tid * 8, &kv[buf][6144 + tid * 8]);
  };

  stagekv(0, 0);
  asm volatile("s_waitcnt vmcnt(0)" ::: "memory");
  __builtin_amdgcn_s_barrier();
  __builtin_amdgcn_sched_barrier(0);

  for (int t = 0; t < NT; ++t) {
    const int cur = t & 1;
    if (t + 1 < NT) stagekv(cur ^ 1, t + 1);

    bf16x8 kf[2][4];
#pragma unroll
    for (int tt = 0; tt < 2; ++tt)
#pragma unroll
      for (int ks = 0; ks < 4; ++ks)
        kf[tt][ks] = *reinterpret_cast<const bf16x8*>(&kv[cur][(tt * 4 + ks) * 512 + lane * 8]);

    // S^T = K Q^T : rows = k, cols = q (l31)
    f32x16 s0 = (f32x16)0.f, s1 = (f32x16)0.f;
    __builtin_amdgcn_s_setprio(1);
#pragma unroll
    for (int ks = 0; ks < 4; ++ks) {
      s0 = mfma32(kf[0][ks], qf[ks], s0);
      s1 = mfma32(kf[1][ks], qf[ks], s1);
    }
    __builtin_amdgcn_s_setprio(0);

    bf16x8 vf[2][4];
#pragma unroll
    for (int dt = 0; dt < 2; ++dt)
#pragma unroll
      for (int ks = 0; ks < 4; ++ks)
        vf[dt][ks] = *reinterpret_cast<const bf16x8*>(&kv[cur][4096 + (dt * 4 + ks) * 512 + lane * 8]);

    // P = exp2(s) lane-local; pack to bf16 pairs (no max subtraction needed)
    unsigned wpk[16];
#pragma unroll
    for (int i = 0; i < 8; ++i) {
      wpk[i]     = packbf(fexp2(s0[2 * i]), fexp2(s0[2 * i + 1]));
      wpk[8 + i] = packbf(fexp2(s1[2 * i]), fexp2(s1[2 * i + 1]));
    }

    // half-exchange via permlane32_swap
    u32x4 fw[4];
#pragma unroll
    for (int fi = 0; fi < 4; ++fi) {
      unsigned a0 = wpk[fi * 4 + 0], b0 = wpk[fi * 4 + 2];
      unsigned a1 = wpk[fi * 4 + 1], b1 = wpk[fi * 4 + 3];
      asm("v_permlane32_swap_b32 %0, %1" : "+v"(a0), "+v"(b0));
      asm("v_permlane32_swap_b32 %0, %1" : "+v"(a1), "+v"(b1));
      fw[fi] = u32x4{a0, a1, b0, b1};
    }

    // O += P V ; row-sum += P * ones  (denominator in the matrix pipe, same C layout)
    __builtin_amdgcn_s_setprio(1);
#pragma unroll
    for (int ks = 0; ks < 4; ++ks) {
      const bf16x8 pf = __builtin_bit_cast(bf16x8, fw[ks]);
      o0   = mfma32(pf, vf[0][ks], o0);
      o1   = mfma32(pf, vf[1][ks], o1);
      osum = mfma32(pf, onesf, osum);
    }
    __builtin_amdgcn_s_setprio(0);

    if (t + 1 < NT) {
      asm volatile("s_waitcnt vmcnt(0)" ::: "memory");
      __builtin_amdgcn_s_barrier();
      __builtin_amdgcn_sched_barrier(0);
    }
  }

  // normalize + store: osum[r] matches o0[r]/o1[r] row-for-row
  bf16* obase = att + ((size_t)b * S + q0) * U + h * DH + l31;
#pragma unroll
  for (int r = 0; r < 16; ++r) {
    const int row = (r & 3) + 8 * (r >> 2) + 4 * hi8;
    const float lr = 1.f / osum[r];
    obase[(size_t)row * U]      = (bf16)(o0[r] * lr);
    obase[(size_t)row * U + 32] = (bf16)(o1[r] * lr);
  }
}

// ---------- epilogue: x = relu(att + vres); LayerNorm(x)*gamma + beta ----------
// One WAVE per row (no LDS, no __syncthreads), 4 rows per 256-thread block.
__global__ __launch_bounds__(256) void ln_kernel(
    const bf16* __restrict__ att, const bf16* __restrict__ vres,
    const float* __restrict__ gamma, const float* __restrict__ beta,
    float* __restrict__ out) {
  const int w = threadIdx.x >> 6, lane = threadIdx.x & 63;
  const int row = blockIdx.x * 4 + w;
  const int c0 = lane * 16;
  const bf16* ar = att  + (size_t)row * U + c0;
  const bf16* vr = vres + (size_t)row * U + c0;

  const bf16x8 a0 = *reinterpret_cast<const bf16x8*>(ar);
  const bf16x8 a1 = *reinterpret_cast<const bf16x8*>(ar + 8);
  const bf16x8 v0 = *reinterpret_cast<const bf16x8*>(vr);
  const bf16x8 v1 = *reinterpret_cast<const bf16x8*>(vr + 8);

  float x[16];
  float sum = 0.f, sq = 0.f;
#pragma unroll
  for (int i = 0; i < 8; ++i) {
    x[i]     = fmaxf((float)a0[i] + (float)v0[i], 0.f);
    x[8 + i] = fmaxf((float)a1[i] + (float)v1[i], 0.f);
  }
#pragma unroll
  for (int i = 0; i < 16; ++i) { sum += x[i]; sq += x[i] * x[i]; }
#pragma unroll
  for (int mm = 1; mm < 64; mm <<= 1) {
    sum += __shfl_xor(sum, mm);
    sq  += __shfl_xor(sq, mm);
  }
  const float mean = sum * (1.f / U);
  float var = sq * (1.f / U) - mean * mean;
  var = fmaxf(var, 0.f);
  const float inv = rsqrtf(var + 1e-8f);

  float* orow = out + (size_t)row * U + c0;
#pragma unroll
  for (int j = 0; j < 4; ++j) {
    const float4 g = *reinterpret_cast<const float4*>(gamma + c0 + j * 4);
    const float4 bt = *reinterpret_cast<const float4*>(beta + c0 + j * 4);
    float4 o;
    o.x = g.x * ((x[j * 4 + 0] - mean) * inv) + bt.x;
    o.y = g.y * ((x[j * 4 + 1] - mean) * inv) + bt.y;
    o.z = g.z * ((x[j * 4 + 2] - mean) * inv) + bt.z;
    o.w = g.w * ((x[j * 4 + 3] - mean) * inv) + bt.w;
    *reinterpret_cast<float4*>(orow + j * 4) = o;
  }
}

extern "C" void kernel_launch(void* const* d_in, const int* in_sizes, int n_in,
                              void* d_out, int out_size, void* d_ws, size_t ws_size,
                              hipStream_t stream) {
  const float* queries = (const float*)d_in[0];
  const float* keys    = (const float*)d_in[1];
  const float* values  = (const float*)d_in[2];
  const float* Wq = (const float*)d_in[3];
  const float* bq = (const float*)d_in[4];
  const float* Wk = (const float*)d_in[5];
  const float* bk = (const float*)d_in[6];
  const float* Wv = (const float*)d_in[7];
  const float* bv = (const float*)d_in[8];
  const float* Wr = (const float*)d_in[9];
  const float* br = (const float*)d_in[10];
  const float* gamma = (const float*)d_in[11];
  const float* beta  = (const float*)d_in[12];
  float* out = (float*)d_out;

  char* ws = (char*)d_ws;
  const size_t MB = 1024 * 1024;
  bf16* wqt  = (bf16*)(ws + 0 * MB);
  bf16* wkt  = (bf16*)(ws + 2 * MB);
  bf16* wvt  = (bf16*)(ws + 4 * MB);
  bf16* wrt  = (bf16*)(ws + 6 * MB);
  bf16* Qcvt = (bf16*)(ws + 8 * MB);    // dead after gemm -> attb aliases
  bf16* Kcvt = (bf16*)(ws + 24 * MB);   // dead after gemm -> Rb aliases (Rb written by gemm z=3)
  bf16* Vcvt = (bf16*)(ws + 40 * MB);
  bf16* Qb   = (bf16*)(ws + 56 * MB);
  bf16* Kp   = (bf16*)(ws + 72 * MB);
  bf16* Vp   = (bf16*)(ws + 88 * MB);   // total 104 MB
  bf16* attb = Qcvt;
  bf16* Rb   = Kcvt;

  prep_kernel<<<dim3(16384), 256, 0, stream>>>(
      queries, keys, values, Qcvt, Kcvt, Vcvt,
      Wq, Wk, Wv, Wr, wqt, wkt, wvt, wrt);
  gemm4_kernel<<<dim3(512), 512, 0, stream>>>(
      Qcvt, Kcvt, Vcvt, wqt, wkt, wvt, wrt, bq, bk, bv, br, Qb, Kp, Vp, Rb);
  attn_kernel<<<dim3(1024), 256, 0, stream>>>(Qb, Kp, Vp, attb);
  ln_kernel<<<dim3(MTOT / 4), 256, 0, stream>>>(attb, Rb, gamma, beta, out);
}

// Round 18
// 199.267 us; speedup vs baseline: 1.1675x; 1.0114x over previous
//
#include <hip/hip_runtime.h>

constexpr int B = 4, S = 2048, U = 1024, H = 16, DH = 64;
constexpr int MTOT = B * S;
constexpr int NT = S / 64;   // 32 key-tiles of 64

using bf16   = __bf16;
using f32x4  = __attribute__((ext_vector_type(4))) float;
using f32x16 = __attribute__((ext_vector_type(16))) float;
using bf16x8 = __attribute__((ext_vector_type(8))) bf16;
using bf16x4 = __attribute__((ext_vector_type(4))) bf16;
using u32x4  = __attribute__((ext_vector_type(4))) unsigned int;

__device__ __forceinline__ void gload16(const bf16* g, bf16* l) {
  __builtin_amdgcn_global_load_lds(
      (const __attribute__((address_space(1))) unsigned int*)g,
      (__attribute__((address_space(3))) unsigned int*)l, 16, 0, 0);
}

__device__ __forceinline__ float fexp2(float x) {
#if __has_builtin(__builtin_amdgcn_exp2f)
  return __builtin_amdgcn_exp2f(x);
#else
  return __expf(x * 0.6931471805599453f);
#endif
}

__device__ __forceinline__ f32x16 mfma32(bf16x8 a, bf16x8 b, f32x16 c) {
  return __builtin_amdgcn_mfma_f32_32x32x16_bf16(a, b, c, 0, 0, 0);
}

__device__ __forceinline__ unsigned packbf(float a, float b) {
  union { bf16 h; unsigned short s; } ua, ub;
  ua.h = (bf16)a; ub.h = (bf16)b;
  return ((unsigned)ub.s << 16) | (unsigned)ua.s;
}

// packed K layout: Kp[bh][t][tt][ks][ln][8] = K[s = t*64+tt*32+(ln&31)][h*64 + ks*16+(ln>>5)*8+j]
__device__ __forceinline__ size_t kpack_off(int M_, int col) {
  const int b = M_ >> 11, s = M_ & 2047;
  const int h = col >> 6, d = col & 63;
  const int bh = b * 16 + h;
  const int t = s >> 6, r64 = s & 63;
  const int tt = r64 >> 5, l31 = r64 & 31;
  const int ks = d >> 4, hi = (d >> 3) & 1, j = d & 7;
  const int ln = l31 + (hi << 5);
  return ((size_t)(bh * 32 + t) << 12) + (tt << 11) + (ks << 9) + (ln << 3) + j;
}

// packed V layout: Vp[bh][t][dt][ks][ln][8] = V[s = t*64+ks*16+(ln>>5)*8+j][h*64 + dt*32+(ln&31)]
__device__ __forceinline__ size_t vpack_off(int M_, int col) {
  const int b = M_ >> 11, s = M_ & 2047;
  const int h = col >> 6, d = col & 63;
  const int bh = b * 16 + h;
  const int j = s & 7, hi = (s >> 3) & 1, ks = (s >> 4) & 3, t = s >> 6;
  const int dt = d >> 5, l31 = d & 31;
  const int ln = l31 + (hi << 5);
  return ((size_t)(bh * 32 + t) << 12) + (dt << 11) + (ks << 9) + (ln << 3) + j;
}

// ---------- prep: fused {fp32->bf16 convert of q,k,v} + {4x weight transpose+convert} ----------
__global__ __launch_bounds__(256) void prep_kernel(
    const float* __restrict__ xq, const float* __restrict__ xk, const float* __restrict__ xv,
    bf16* __restrict__ oq, bf16* __restrict__ ok, bf16* __restrict__ ov,
    const float* __restrict__ w0, const float* __restrict__ w1,
    const float* __restrict__ w2, const float* __restrict__ w3,
    bf16* __restrict__ t0, bf16* __restrict__ t1,
    bf16* __restrict__ t2, bf16* __restrict__ t3) {
  __shared__ float tile[32][33];
  const int bid = blockIdx.x;
  const int t = threadIdx.x;
  if (bid < 12288) {
    const int z = bid >> 12, idx = bid & 4095;
    const float* x = z == 0 ? xq : z == 1 ? xk : xv;
    bf16* o       = z == 0 ? oq : z == 1 ? ok : ov;
    const size_t i = ((size_t)idx * 256 + t) * 8;
    const float4 v0 = *reinterpret_cast<const float4*>(x + i);
    const float4 v1 = *reinterpret_cast<const float4*>(x + i + 4);
    bf16x8 r;
    r[0] = (bf16)v0.x; r[1] = (bf16)v0.y; r[2] = (bf16)v0.z; r[3] = (bf16)v0.w;
    r[4] = (bf16)v1.x; r[5] = (bf16)v1.y; r[6] = (bf16)v1.z; r[7] = (bf16)v1.w;
    *reinterpret_cast<bf16x8*>(o + i) = r;
  } else {
    const int wb = bid - 12288;
    const int z = wb >> 10, ti = wb & 1023;
    const float* W = z == 0 ? w0 : z == 1 ? w1 : z == 2 ? w2 : w3;
    bf16* Wt       = z == 0 ? t0 : z == 1 ? t1 : z == 2 ? t2 : t3;
    const int k0 = (ti & 31) * 32, n0 = (ti >> 5) * 32;
    const int tx = t & 31, ty = t >> 5;
    for (int i = ty; i < 32; i += 8) tile[i][tx] = W[(size_t)(k0 + i) * U + n0 + tx];
    __syncthreads();
    for (int i = ty; i < 32; i += 8) Wt[(size_t)(n0 + i) * U + k0 + tx] = (bf16)tile[tx][i];
  }
}

// ---------- fused 4-GEMM: out = relu(A @ Wt^T + b) ----------
// 256x256 template, 8 waves (2M x 4N), BK=64, 128KB LDS 2-buffer. Staging is
// issue-early: ALL of K-tile t+1 staged in phases 0-1; phases 2-3 MFMA-only, so the
// newest load has ~2 phases (>=500cy) before the single per-tile vmcnt(0)+barrier.
// r12-verified slot swizzle: LDS[r][s] = data[r][s ^ (r&7)]; read slot (ks*4+hi)^(lm&7).
__global__ __launch_bounds__(512, 2) void gemm4_kernel(
    const bf16* __restrict__ Qc, const bf16* __restrict__ Kc, const bf16* __restrict__ Vc,
    const bf16* __restrict__ wqt, const bf16* __restrict__ wkt,
    const bf16* __restrict__ wvt, const bf16* __restrict__ wrt,
    const float* __restrict__ bq, const float* __restrict__ bk,
    const float* __restrict__ bv, const float* __restrict__ br,
    bf16* __restrict__ oq, bf16* __restrict__ okp,
    bf16* __restrict__ ovp, bf16* __restrict__ orr) {
  const int bid = blockIdx.x;
  const int wg = (bid & 7) * 64 + (bid >> 3);   // bijective: 512 % 8 == 0
  const int z = wg >> 7, rem = wg & 127;
  const int bm = (rem >> 2) * 256, bn = (rem & 3) * 256;

  const bf16* A     = z == 0 ? Qc : z == 1 ? Kc : Vc;   // z==2,3 read Vcvt
  const bf16* Wt    = z == 0 ? wqt : z == 1 ? wkt : z == 2 ? wvt : wrt;
  const float* bias = z == 0 ? bq : z == 1 ? bk : z == 2 ? bv : br;

  const int tid = threadIdx.x, lane = tid & 63, w = tid >> 6;
  const int wr = w >> 2, wcn = w & 3;
  const int lm = lane & 15, hi = lane >> 4;

  __shared__ __align__(16) bf16 smem[65536];   // 128KB: [buf][A 16384 | B 16384]

  f32x4 acc[8][4];
#pragma unroll
  for (int i = 0; i < 8; ++i)
#pragma unroll
    for (int j = 0; j < 4; ++j) acc[i][j] = f32x4{0.f, 0.f, 0.f, 0.f};

  const int srow = tid >> 3, sslot = tid & 7;
  const int scol = (sslot ^ (srow & 7)) * 8;
  const bf16* gA = A  + (size_t)(bm + srow) * U + scol;
  const bf16* gB = Wt + (size_t)(bn + srow) * U + scol;

  auto stageA = [&](int buf, int half, int k0) {
    bf16* l = smem + buf * 32768 + (half * 128 + srow) * 64 + sslot * 8;
    gload16(gA + (size_t)(half * 128) * U + k0, l);
    gload16(gA + (size_t)(half * 128 + 64) * U + k0, l + 64 * 64);
  };
  auto stageB = [&](int buf, int half, int k0) {
    bf16* l = smem + buf * 32768 + 16384 + (half * 128 + srow) * 64 + sslot * 8;
    gload16(gB + (size_t)(half * 128) * U + k0, l);
    gload16(gB + (size_t)(half * 128 + 64) * U + k0, l + 64 * 64);
  };

  auto loadA = [&](int buf, int mi, int ks) {
    const int row = wr * 128 + mi * 16 + lm;
    const int slot = (ks * 4 + hi) ^ (lm & 7);
    return *reinterpret_cast<const bf16x8*>(smem + buf * 32768 + row * 64 + slot * 8);
  };
  auto loadB = [&](int buf, int ni, int ks) {
    const int row = wcn * 64 + ni * 16 + lm;
    const int slot = (ks * 4 + hi) ^ (lm & 7);
    return *reinterpret_cast<const bf16x8*>(smem + buf * 32768 + 16384 + row * 64 + slot * 8);
  };

  stageA(0, 0, 0); stageA(0, 1, 0); stageB(0, 0, 0); stageB(0, 1, 0);
  asm volatile("s_waitcnt vmcnt(0)" ::: "memory");
  __builtin_amdgcn_s_barrier();
  __builtin_amdgcn_sched_barrier(0);

  for (int t = 0; t < 16; ++t) {
    const int buf = t & 1, nbf = buf ^ 1;
    const int k1 = (t + 1) * 64;
    const bool pre = (t + 1) < 16;

    bf16x8 bfr[4][2];

    // ---- phase 0: stage A(t+1) fully; B-frags + quadrant mi {0,1}
    if (pre) { stageA(nbf, 0, k1); stageA(nbf, 1, k1); }
#pragma unroll
    for (int ni = 0; ni < 4; ++ni) {
      bfr[ni][0] = loadB(buf, ni, 0);
      bfr[ni][1] = loadB(buf, ni, 1);
    }
    {
      bf16x8 a00 = loadA(buf, 0, 0), a01 = loadA(buf, 0, 1);
      bf16x8 a10 = loadA(buf, 1, 0), a11 = loadA(buf, 1, 1);
      __builtin_amdgcn_s_setprio(1);
#pragma unroll
      for (int ni = 0; ni < 4; ++ni) {
        acc[0][ni] = __builtin_amdgcn_mfma_f32_16x16x32_bf16(a00, bfr[ni][0], acc[0][ni], 0, 0, 0);
        acc[0][ni] = __builtin_amdgcn_mfma_f32_16x16x32_bf16(a01, bfr[ni][1], acc[0][ni], 0, 0, 0);
        acc[1][ni] = __builtin_amdgcn_mfma_f32_16x16x32_bf16(a10, bfr[ni][0], acc[1][ni], 0, 0, 0);
        acc[1][ni] = __builtin_amdgcn_mfma_f32_16x16x32_bf16(a11, bfr[ni][1], acc[1][ni], 0, 0, 0);
      }
      __builtin_amdgcn_s_setprio(0);
    }
    // ---- phase 1: stage B(t+1) fully; quadrant mi {2,3}
    if (pre) { stageB(nbf, 0, k1); stageB(nbf, 1, k1); }
    {
      bf16x8 a00 = loadA(buf, 2, 0), a01 = loadA(buf, 2, 1);
      bf16x8 a10 = loadA(buf, 3, 0), a11 = loadA(buf, 3, 1);
      __builtin_amdgcn_s_setprio(1);
#pragma unroll
      for (int ni = 0; ni < 4; ++ni) {
        acc[2][ni] = __builtin_amdgcn_mfma_f32_16x16x32_bf16(a00, bfr[ni][0], acc[2][ni], 0, 0, 0);
        acc[2][ni] = __builtin_amdgcn_mfma_f32_16x16x32_bf16(a01, bfr[ni][1], acc[2][ni], 0, 0, 0);
        acc[3][ni] = __builtin_amdgcn_mfma_f32_16x16x32_bf16(a10, bfr[ni][0], acc[3][ni], 0, 0, 0);
        acc[3][ni] = __builtin_amdgcn_mfma_f32_16x16x32_bf16(a11, bfr[ni][1], acc[3][ni], 0, 0, 0);
      }
      __builtin_amdgcn_s_setprio(0);
    }
    // ---- phase 2: quadrant mi {4,5}
    {
      bf16x8 a00 = loadA(buf, 4, 0), a01 = loadA(buf, 4, 1);
      bf16x8 a10 = loadA(buf, 5, 0), a11 = loadA(buf, 5, 1);
      __builtin_amdgcn_s_setprio(1);
#pragma unroll
      for (int ni = 0; ni < 4; ++ni) {
        acc[4][ni] = __builtin_amdgcn_mfma_f32_16x16x32_bf16(a00, bfr[ni][0], acc[4][ni], 0, 0, 0);
        acc[4][ni] = __builtin_amdgcn_mfma_f32_16x16x32_bf16(a01, bfr[ni][1], acc[4][ni], 0, 0, 0);
        acc[5][ni] = __builtin_amdgcn_mfma_f32_16x16x32_bf16(a10, bfr[ni][0], acc[5][ni], 0, 0, 0);
        acc[5][ni] = __builtin_amdgcn_mfma_f32_16x16x32_bf16(a11, bfr[ni][1], acc[5][ni], 0, 0, 0);
      }
      __builtin_amdgcn_s_setprio(0);
    }
    // ---- phase 3: quadrant mi {6,7}
    {
      bf16x8 a00 = loadA(buf, 6, 0), a01 = loadA(buf, 6, 1);
      bf16x8 a10 = loadA(buf, 7, 0), a11 = loadA(buf, 7, 1);
      __builtin_amdgcn_s_setprio(1);
#pragma unroll
      for (int ni = 0; ni < 4; ++ni) {
        acc[6][ni] = __builtin_amdgcn_mfma_f32_16x16x32_bf16(a00, bfr[ni][0], acc[6][ni], 0, 0, 0);
        acc[6][ni] = __builtin_amdgcn_mfma_f32_16x16x32_bf16(a01, bfr[ni][1], acc[6][ni], 0, 0, 0);
        acc[7][ni] = __builtin_amdgcn_mfma_f32_16x16x32_bf16(a10, bfr[ni][0], acc[7][ni], 0, 0, 0);
        acc[7][ni] = __builtin_amdgcn_mfma_f32_16x16x32_bf16(a11, bfr[ni][1], acc[7][ni], 0, 0, 0);
      }
      __builtin_amdgcn_s_setprio(0);
    }

    if (pre) {
      asm volatile("s_waitcnt vmcnt(0)" ::: "memory");
      __builtin_amdgcn_s_barrier();
      __builtin_amdgcn_sched_barrier(0);
    }
  }

  const int mb = bm + wr * 128 + hi * 4;
  const int nb = bn + wcn * 64 + lm;
  if (z == 1) {
#pragma unroll
    for (int ni = 0; ni < 4; ++ni) {
      const float bv_ = bias[nb + ni * 16];
#pragma unroll
      for (int mi = 0; mi < 8; ++mi)
#pragma unroll
        for (int r = 0; r < 4; ++r) {
          const float vv = fmaxf(acc[mi][ni][r] + bv_, 0.f);
          okp[kpack_off(mb + mi * 16 + r, nb + ni * 16)] = (bf16)vv;
        }
    }
  } else if (z == 2) {
#pragma unroll
    for (int ni = 0; ni < 4; ++ni) {
      const float bv_ = bias[nb + ni * 16];
#pragma unroll
      for (int mi = 0; mi < 8; ++mi)
#pragma unroll
        for (int r = 0; r < 4; ++r) {
          const float vv = fmaxf(acc[mi][ni][r] + bv_, 0.f);
          ovp[vpack_off(mb + mi * 16 + r, nb + ni * 16)] = (bf16)vv;
        }
    }
  } else {
    bf16* out = z == 0 ? oq : orr;
#pragma unroll
    for (int ni = 0; ni < 4; ++ni) {
      const float bv_ = bias[nb + ni * 16];
#pragma unroll
      for (int mi = 0; mi < 8; ++mi)
#pragma unroll
        for (int r = 0; r < 4; ++r) {
          const float vv = fmaxf(acc[mi][ni][r] + bv_, 0.f);
          out[(size_t)(mb + mi * 16 + r) * U + nb + ni * 16] = (bf16)vv;
        }
    }
  }
}

// ---------- flash attention: packed K/V, 2-buffer LDS, 64 q-rows PER WAVE ----------
// LDS-BW was the binding constraint (16 ds_read_b128/wave-tile, 8 waves -> ~96% of
// the LDS pipe). Each wave now covers TWO 32-row q-groups with the SAME fragment
// reads: LDS reads + staging per FLOP halve. Swapped QK^T (32x32x16); no-max
// softmax; osum via ones-MFMA; half-exchange via v_permlane32_swap_b32.
__global__ __launch_bounds__(256, 2) void attn_kernel(
    const bf16* __restrict__ Q, const bf16* __restrict__ Kp,
    const bf16* __restrict__ Vp, bf16* __restrict__ att) {
  const int bid = blockIdx.x;
  const int swz = (bid & 7) * 64 + (bid >> 3);     // 512 blocks, 8 per XCD chunk
  const int bh = swz >> 3, qx = swz & 7;
  const int b = bh >> 4, h = bh & 15;
  const int tid = threadIdx.x;
  const int w = tid >> 6, lane = tid & 63;
  const int l31 = lane & 31, hi8 = lane >> 5;
  const int q0 = qx * 256 + w * 64;

  __shared__ __align__(16) bf16 kv[2][8192];   // [0..4095]=K tile, [4096..8191]=V tile

  const float qscale = 0.18033688011111606f;  // log2(e)/sqrt(DH)

  // Q fragments for both q-groups (B operand: col = q = l31)
  bf16x8 qf[2][4];
#pragma unroll
  for (int qg = 0; qg < 2; ++qg) {
    const bf16* qbase = Q + ((size_t)b * S + q0 + qg * 32 + l31) * U + h * DH + hi8 * 8;
#pragma unroll
    for (int ks = 0; ks < 4; ++ks) {
      bf16x8 v = *reinterpret_cast<const bf16x8*>(qbase + ks * 16);
#pragma unroll
      for (int j = 0; j < 8; ++j) v[j] = (bf16)((float)v[j] * qscale);
      qf[qg][ks] = v;
    }
  }

  bf16x8 onesf;
#pragma unroll
  for (int j = 0; j < 8; ++j) onesf[j] = (bf16)1.f;

  f32x16 o[2][2], osum[2];
#pragma unroll
  for (int qg = 0; qg < 2; ++qg) {
    o[qg][0] = (f32x16)0.f; o[qg][1] = (f32x16)0.f; osum[qg] = (f32x16)0.f;
  }

  const bf16* kpb = Kp + (size_t)bh * 32 * 4096;
  const bf16* vpb = Vp + (size_t)bh * 32 * 4096;

  auto stagekv = [&](int buf, int t) {
    const size_t toff = (size_t)t * 4096;
    gload16(kpb + toff + tid * 8,        &kv[buf][tid * 8]);
    gload16(kpb + toff + 2048 + tid * 8, &kv[buf][2048 + tid * 8]);
    gload16(vpb + toff + tid * 8,        &kv[buf][4096 + tid * 8]);
    gload16(vpb + toff + 2048 + tid * 8, &kv[buf][6144 + tid * 8]);
  };

  stagekv(0, 0);
  asm volatile("s_waitcnt vmcnt(0)" ::: "memory");
  __builtin_amdgcn_s_barrier();
  __builtin_amdgcn_sched_barrier(0);

  for (int t = 0; t < NT; ++t) {
    const int cur = t & 1;
    if (t + 1 < NT) stagekv(cur ^ 1, t + 1);

    // S^T = K Q^T for both q-groups; kf loaded in tt-halves to cap VGPR
    f32x16 s[2][2];
    s[0][0] = (f32x16)0.f; s[0][1] = (f32x16)0.f;
    s[1][0] = (f32x16)0.f; s[1][1] = (f32x16)0.f;
#pragma unroll
    for (int tt = 0; tt < 2; ++tt) {
      bf16x8 kf4[4];
#pragma unroll
      for (int ks = 0; ks < 4; ++ks)
        kf4[ks] = *reinterpret_cast<const bf16x8*>(&kv[cur][(tt * 4 + ks) * 512 + lane * 8]);
      __builtin_amdgcn_s_setprio(1);
#pragma unroll
      for (int ks = 0; ks < 4; ++ks) {
        s[0][tt] = mfma32(kf4[ks], qf[0][ks], s[0][tt]);
        s[1][tt] = mfma32(kf4[ks], qf[1][ks], s[1][tt]);
      }
      __builtin_amdgcn_s_setprio(0);
    }

    // P = exp2(s); pack; half-exchange. fw[qg][ks] = A-fragment of P.
    u32x4 fw[2][4];
#pragma unroll
    for (int qg = 0; qg < 2; ++qg) {
      unsigned wpk[16];
#pragma unroll
      for (int i = 0; i < 8; ++i) {
        wpk[i]     = packbf(fexp2(s[qg][0][2 * i]), fexp2(s[qg][0][2 * i + 1]));
        wpk[8 + i] = packbf(fexp2(s[qg][1][2 * i]), fexp2(s[qg][1][2 * i + 1]));
      }
#pragma unroll
      for (int fi = 0; fi < 4; ++fi) {
        unsigned a0 = wpk[fi * 4 + 0], b0 = wpk[fi * 4 + 2];
        unsigned a1 = wpk[fi * 4 + 1], b1 = wpk[fi * 4 + 3];
        asm("v_permlane32_swap_b32 %0, %1" : "+v"(a0), "+v"(b0));
        asm("v_permlane32_swap_b32 %0, %1" : "+v"(a1), "+v"(b1));
        fw[qg][fi] = u32x4{a0, a1, b0, b1};
      }
    }

    // O += P V (vf loaded in dt-halves); osum += P * ones
#pragma unroll
    for (int dt = 0; dt < 2; ++dt) {
      bf16x8 vf4[4];
#pragma unroll
      for (int ks = 0; ks < 4; ++ks)
        vf4[ks] = *reinterpret_cast<const bf16x8*>(&kv[cur][4096 + (dt * 4 + ks) * 512 + lane * 8]);
      __builtin_amdgcn_s_setprio(1);
#pragma unroll
      for (int ks = 0; ks < 4; ++ks) {
        o[0][dt] = mfma32(__builtin_bit_cast(bf16x8, fw[0][ks]), vf4[ks], o[0][dt]);
        o[1][dt] = mfma32(__builtin_bit_cast(bf16x8, fw[1][ks]), vf4[ks], o[1][dt]);
      }
      __builtin_amdgcn_s_setprio(0);
    }
    __builtin_amdgcn_s_setprio(1);
#pragma unroll
    for (int ks = 0; ks < 4; ++ks) {
      osum[0] = mfma32(__builtin_bit_cast(bf16x8, fw[0][ks]), onesf, osum[0]);
      osum[1] = mfma32(__builtin_bit_cast(bf16x8, fw[1][ks]), onesf, osum[1]);
    }
    __builtin_amdgcn_s_setprio(0);

    if (t + 1 < NT) {
      asm volatile("s_waitcnt vmcnt(0)" ::: "memory");
      __builtin_amdgcn_s_barrier();
      __builtin_amdgcn_sched_barrier(0);
    }
  }

  // normalize + store: osum[qg][r] matches o[qg][*][r] row-for-row
#pragma unroll
  for (int qg = 0; qg < 2; ++qg) {
    bf16* obase = att + ((size_t)b * S + q0 + qg * 32) * U + h * DH + l31;
#pragma unroll
    for (int r = 0; r < 16; ++r) {
      const int row = (r & 3) + 8 * (r >> 2) + 4 * hi8;
      const float lr = 1.f / osum[qg][r];
      obase[(size_t)row * U]      = (bf16)(o[qg][0][r] * lr);
      obase[(size_t)row * U + 32] = (bf16)(o[qg][1][r] * lr);
    }
  }
}

// ---------- epilogue: x = relu(att + vres); LayerNorm(x)*gamma + beta ----------
// One WAVE per row (no LDS, no __syncthreads), 4 rows per 256-thread block.
__global__ __launch_bounds__(256) void ln_kernel(
    const bf16* __restrict__ att, const bf16* __restrict__ vres,
    const float* __restrict__ gamma, const float* __restrict__ beta,
    float* __restrict__ out) {
  const int w = threadIdx.x >> 6, lane = threadIdx.x & 63;
  const int row = blockIdx.x * 4 + w;
  const int c0 = lane * 16;
  const bf16* ar = att  + (size_t)row * U + c0;
  const bf16* vr = vres + (size_t)row * U + c0;

  const bf16x8 a0 = *reinterpret_cast<const bf16x8*>(ar);
  const bf16x8 a1 = *reinterpret_cast<const bf16x8*>(ar + 8);
  const bf16x8 v0 = *reinterpret_cast<const bf16x8*>(vr);
  const bf16x8 v1 = *reinterpret_cast<const bf16x8*>(vr + 8);

  float x[16];
  float sum = 0.f, sq = 0.f;
#pragma unroll
  for (int i = 0; i < 8; ++i) {
    x[i]     = fmaxf((float)a0[i] + (float)v0[i], 0.f);
    x[8 + i] = fmaxf((float)a1[i] + (float)v1[i], 0.f);
  }
#pragma unroll
  for (int i = 0; i < 16; ++i) { sum += x[i]; sq += x[i] * x[i]; }
#pragma unroll
  for (int mm = 1; mm < 64; mm <<= 1) {
    sum += __shfl_xor(sum, mm);
    sq  += __shfl_xor(sq, mm);
  }
  const float mean = sum * (1.f / U);
  float var = sq * (1.f / U) - mean * mean;
  var = fmaxf(var, 0.f);
  const float inv = rsqrtf(var + 1e-8f);

  float* orow = out + (size_t)row * U + c0;
#pragma unroll
  for (int j = 0; j < 4; ++j) {
    const float4 g = *reinterpret_cast<const float4*>(gamma + c0 + j * 4);
    const float4 bt = *reinterpret_cast<const float4*>(beta + c0 + j * 4);
    float4 o;
    o.x = g.x * ((x[j * 4 + 0] - mean) * inv) + bt.x;
    o.y = g.y * ((x[j * 4 + 1] - mean) * inv) + bt.y;
    o.z = g.z * ((x[j * 4 + 2] - mean) * inv) + bt.z;
    o.w = g.w * ((x[j * 4 + 3] - mean) * inv) + bt.w;
    *reinterpret_cast<float4*>(orow + j * 4) = o;
  }
}

extern "C" void kernel_launch(void* const* d_in, const int* in_sizes, int n_in,
                              void* d_out, int out_size, void* d_ws, size_t ws_size,
                              hipStream_t stream) {
  const float* queries = (const float*)d_in[0];
  const float* keys    = (const float*)d_in[1];
  const float* values  = (const float*)d_in[2];
  const float* Wq = (const float*)d_in[3];
  const float* bq = (const float*)d_in[4];
  const float* Wk = (const float*)d_in[5];
  const float* bk = (const float*)d_in[6];
  const float* Wv = (const float*)d_in[7];
  const float* bv = (const float*)d_in[8];
  const float* Wr = (const float*)d_in[9];
  const float* br = (const float*)d_in[10];
  const float* gamma = (const float*)d_in[11];
  const float* beta  = (const float*)d_in[12];
  float* out = (float*)d_out;

  char* ws = (char*)d_ws;
  const size_t MB = 1024 * 1024;
  bf16* wqt  = (bf16*)(ws + 0 * MB);
  bf16* wkt  = (bf16*)(ws + 2 * MB);
  bf16* wvt  = (bf16*)(ws + 4 * MB);
  bf16* wrt  = (bf16*)(ws + 6 * MB);
  bf16* Qcvt = (bf16*)(ws + 8 * MB);    // dead after gemm -> attb aliases
  bf16* Kcvt = (bf16*)(ws + 24 * MB);   // dead after gemm -> Rb aliases (Rb written by gemm z=3)
  bf16* Vcvt = (bf16*)(ws + 40 * MB);
  bf16* Qb   = (bf16*)(ws + 56 * MB);
  bf16* Kp   = (bf16*)(ws + 72 * MB);
  bf16* Vp   = (bf16*)(ws + 88 * MB);   // total 104 MB
  bf16* attb = Qcvt;
  bf16* Rb   = Kcvt;

  prep_kernel<<<dim3(16384), 256, 0, stream>>>(
      queries, keys, values, Qcvt, Kcvt, Vcvt,
      Wq, Wk, Wv, Wr, wqt, wkt, wvt, wrt);
  gemm4_kernel<<<dim3(512), 512, 0, stream>>>(
      Qcvt, Kcvt, Vcvt, wqt, wkt, wvt, wrt, bq, bk, bv, br, Qb, Kp, Vp, Rb);
  attn_kernel<<<dim3(512), 256, 0, stream>>>(Qb, Kp, Vp, attb);
  ln_kernel<<<dim3(MTOT / 4), 256, 0, stream>>>(attb, Rb, gamma, beta, out);
}

// Round 19
// 198.114 us; speedup vs baseline: 1.1743x; 1.0058x over previous
//
#include <hip/hip_runtime.h>

constexpr int B = 4, S = 2048, U = 1024, H = 16, DH = 64;
constexpr int MTOT = B * S;
constexpr int NT = S / 64;   // 32 key-tiles of 64

using bf16   = __bf16;
using f32x4  = __attribute__((ext_vector_type(4))) float;
using f32x16 = __attribute__((ext_vector_type(16))) float;
using bf16x8 = __attribute__((ext_vector_type(8))) bf16;
using bf16x4 = __attribute__((ext_vector_type(4))) bf16;
using u32x4  = __attribute__((ext_vector_type(4))) unsigned int;

__device__ __forceinline__ void gload16(const bf16* g, bf16* l) {
  __builtin_amdgcn_global_load_lds(
      (const __attribute__((address_space(1))) unsigned int*)g,
      (__attribute__((address_space(3))) unsigned int*)l, 16, 0, 0);
}

__device__ __forceinline__ float fexp2(float x) {
#if __has_builtin(__builtin_amdgcn_exp2f)
  return __builtin_amdgcn_exp2f(x);
#else
  return __expf(x * 0.6931471805599453f);
#endif
}

__device__ __forceinline__ f32x16 mfma32(bf16x8 a, bf16x8 b, f32x16 c) {
  return __builtin_amdgcn_mfma_f32_32x32x16_bf16(a, b, c, 0, 0, 0);
}

__device__ __forceinline__ unsigned packbf(float a, float b) {
  union { bf16 h; unsigned short s; } ua, ub;
  ua.h = (bf16)a; ub.h = (bf16)b;
  return ((unsigned)ub.s << 16) | (unsigned)ua.s;
}

// packed K layout: Kp[bh][t][tt][ks][ln][8] = K[s = t*64+tt*32+(ln&31)][h*64 + ks*16+(ln>>5)*8+j]
__device__ __forceinline__ size_t kpack_off(int M_, int col) {
  const int b = M_ >> 11, s = M_ & 2047;
  const int h = col >> 6, d = col & 63;
  const int bh = b * 16 + h;
  const int t = s >> 6, r64 = s & 63;
  const int tt = r64 >> 5, l31 = r64 & 31;
  const int ks = d >> 4, hi = (d >> 3) & 1, j = d & 7;
  const int ln = l31 + (hi << 5);
  return ((size_t)(bh * 32 + t) << 12) + (tt << 11) + (ks << 9) + (ln << 3) + j;
}

// packed V layout: Vp[bh][t][dt][ks][ln][8] = V[s = t*64+ks*16+(ln>>5)*8+j][h*64 + dt*32+(ln&31)]
__device__ __forceinline__ size_t vpack_off(int M_, int col) {
  const int b = M_ >> 11, s = M_ & 2047;
  const int h = col >> 6, d = col & 63;
  const int bh = b * 16 + h;
  const int j = s & 7, hi = (s >> 3) & 1, ks = (s >> 4) & 3, t = s >> 6;
  const int dt = d >> 5, l31 = d & 31;
  const int ln = l31 + (hi << 5);
  return ((size_t)(bh * 32 + t) << 12) + (dt << 11) + (ks << 9) + (ln << 3) + j;
}

// ---------- prep: fused {fp32->bf16 convert of q,k,v} + {4x weight transpose+convert} ----------
__global__ __launch_bounds__(256) void prep_kernel(
    const float* __restrict__ xq, const float* __restrict__ xk, const float* __restrict__ xv,
    bf16* __restrict__ oq, bf16* __restrict__ ok, bf16* __restrict__ ov,
    const float* __restrict__ w0, const float* __restrict__ w1,
    const float* __restrict__ w2, const float* __restrict__ w3,
    bf16* __restrict__ t0, bf16* __restrict__ t1,
    bf16* __restrict__ t2, bf16* __restrict__ t3) {
  __shared__ float tile[32][33];
  const int bid = blockIdx.x;
  const int t = threadIdx.x;
  if (bid < 12288) {
    const int z = bid >> 12, idx = bid & 4095;
    const float* x = z == 0 ? xq : z == 1 ? xk : xv;
    bf16* o       = z == 0 ? oq : z == 1 ? ok : ov;
    const size_t i = ((size_t)idx * 256 + t) * 8;
    const float4 v0 = *reinterpret_cast<const float4*>(x + i);
    const float4 v1 = *reinterpret_cast<const float4*>(x + i + 4);
    bf16x8 r;
    r[0] = (bf16)v0.x; r[1] = (bf16)v0.y; r[2] = (bf16)v0.z; r[3] = (bf16)v0.w;
    r[4] = (bf16)v1.x; r[5] = (bf16)v1.y; r[6] = (bf16)v1.z; r[7] = (bf16)v1.w;
    *reinterpret_cast<bf16x8*>(o + i) = r;
  } else {
    const int wb = bid - 12288;
    const int z = wb >> 10, ti = wb & 1023;
    const float* W = z == 0 ? w0 : z == 1 ? w1 : z == 2 ? w2 : w3;
    bf16* Wt       = z == 0 ? t0 : z == 1 ? t1 : z == 2 ? t2 : t3;
    const int k0 = (ti & 31) * 32, n0 = (ti >> 5) * 32;
    const int tx = t & 31, ty = t >> 5;
    for (int i = ty; i < 32; i += 8) tile[i][tx] = W[(size_t)(k0 + i) * U + n0 + tx];
    __syncthreads();
    for (int i = ty; i < 32; i += 8) Wt[(size_t)(n0 + i) * U + k0 + tx] = (bf16)tile[tx][i];
  }
}

// ---------- fused 4-GEMM: out = relu(A @ Wt^T + b) ----------
// 256x256 template, 8 waves (2M x 4N), BK=64, 128KB LDS 2-buffer. Staging is
// issue-early: ALL of K-tile t+1 staged in phases 0-1; phases 2-3 MFMA-only.
// One vmcnt(0)+barrier per K-tile. r12-verified slot swizzle.
__global__ __launch_bounds__(512, 2) void gemm4_kernel(
    const bf16* __restrict__ Qc, const bf16* __restrict__ Kc, const bf16* __restrict__ Vc,
    const bf16* __restrict__ wqt, const bf16* __restrict__ wkt,
    const bf16* __restrict__ wvt, const bf16* __restrict__ wrt,
    const float* __restrict__ bq, const float* __restrict__ bk,
    const float* __restrict__ bv, const float* __restrict__ br,
    bf16* __restrict__ oq, bf16* __restrict__ okp,
    bf16* __restrict__ ovp, bf16* __restrict__ orr) {
  const int bid = blockIdx.x;
  const int wg = (bid & 7) * 64 + (bid >> 3);   // bijective: 512 % 8 == 0
  const int z = wg >> 7, rem = wg & 127;
  const int bm = (rem >> 2) * 256, bn = (rem & 3) * 256;

  const bf16* A     = z == 0 ? Qc : z == 1 ? Kc : Vc;   // z==2,3 read Vcvt
  const bf16* Wt    = z == 0 ? wqt : z == 1 ? wkt : z == 2 ? wvt : wrt;
  const float* bias = z == 0 ? bq : z == 1 ? bk : z == 2 ? bv : br;

  const int tid = threadIdx.x, lane = tid & 63, w = tid >> 6;
  const int wr = w >> 2, wcn = w & 3;
  const int lm = lane & 15, hi = lane >> 4;

  __shared__ __align__(16) bf16 smem[65536];   // 128KB: [buf][A 16384 | B 16384]

  f32x4 acc[8][4];
#pragma unroll
  for (int i = 0; i < 8; ++i)
#pragma unroll
    for (int j = 0; j < 4; ++j) acc[i][j] = f32x4{0.f, 0.f, 0.f, 0.f};

  const int srow = tid >> 3, sslot = tid & 7;
  const int scol = (sslot ^ (srow & 7)) * 8;
  const bf16* gA = A  + (size_t)(bm + srow) * U + scol;
  const bf16* gB = Wt + (size_t)(bn + srow) * U + scol;

  auto stageA = [&](int buf, int half, int k0) {
    bf16* l = smem + buf * 32768 + (half * 128 + srow) * 64 + sslot * 8;
    gload16(gA + (size_t)(half * 128) * U + k0, l);
    gload16(gA + (size_t)(half * 128 + 64) * U + k0, l + 64 * 64);
  };
  auto stageB = [&](int buf, int half, int k0) {
    bf16* l = smem + buf * 32768 + 16384 + (half * 128 + srow) * 64 + sslot * 8;
    gload16(gB + (size_t)(half * 128) * U + k0, l);
    gload16(gB + (size_t)(half * 128 + 64) * U + k0, l + 64 * 64);
  };

  auto loadA = [&](int buf, int mi, int ks) {
    const int row = wr * 128 + mi * 16 + lm;
    const int slot = (ks * 4 + hi) ^ (lm & 7);
    return *reinterpret_cast<const bf16x8*>(smem + buf * 32768 + row * 64 + slot * 8);
  };
  auto loadB = [&](int buf, int ni, int ks) {
    const int row = wcn * 64 + ni * 16 + lm;
    const int slot = (ks * 4 + hi) ^ (lm & 7);
    return *reinterpret_cast<const bf16x8*>(smem + buf * 32768 + 16384 + row * 64 + slot * 8);
  };

  stageA(0, 0, 0); stageA(0, 1, 0); stageB(0, 0, 0); stageB(0, 1, 0);
  asm volatile("s_waitcnt vmcnt(0)" ::: "memory");
  __builtin_amdgcn_s_barrier();
  __builtin_amdgcn_sched_barrier(0);

  for (int t = 0; t < 16; ++t) {
    const int buf = t & 1, nbf = buf ^ 1;
    const int k1 = (t + 1) * 64;
    const bool pre = (t + 1) < 16;

    bf16x8 bfr[4][2];

    if (pre) { stageA(nbf, 0, k1); stageA(nbf, 1, k1); }
#pragma unroll
    for (int ni = 0; ni < 4; ++ni) {
      bfr[ni][0] = loadB(buf, ni, 0);
      bfr[ni][1] = loadB(buf, ni, 1);
    }
    {
      bf16x8 a00 = loadA(buf, 0, 0), a01 = loadA(buf, 0, 1);
      bf16x8 a10 = loadA(buf, 1, 0), a11 = loadA(buf, 1, 1);
      __builtin_amdgcn_s_setprio(1);
#pragma unroll
      for (int ni = 0; ni < 4; ++ni) {
        acc[0][ni] = __builtin_amdgcn_mfma_f32_16x16x32_bf16(a00, bfr[ni][0], acc[0][ni], 0, 0, 0);
        acc[0][ni] = __builtin_amdgcn_mfma_f32_16x16x32_bf16(a01, bfr[ni][1], acc[0][ni], 0, 0, 0);
        acc[1][ni] = __builtin_amdgcn_mfma_f32_16x16x32_bf16(a10, bfr[ni][0], acc[1][ni], 0, 0, 0);
        acc[1][ni] = __builtin_amdgcn_mfma_f32_16x16x32_bf16(a11, bfr[ni][1], acc[1][ni], 0, 0, 0);
      }
      __builtin_amdgcn_s_setprio(0);
    }
    if (pre) { stageB(nbf, 0, k1); stageB(nbf, 1, k1); }
    {
      bf16x8 a00 = loadA(buf, 2, 0), a01 = loadA(buf, 2, 1);
      bf16x8 a10 = loadA(buf, 3, 0), a11 = loadA(buf, 3, 1);
      __builtin_amdgcn_s_setprio(1);
#pragma unroll
      for (int ni = 0; ni < 4; ++ni) {
        acc[2][ni] = __builtin_amdgcn_mfma_f32_16x16x32_bf16(a00, bfr[ni][0], acc[2][ni], 0, 0, 0);
        acc[2][ni] = __builtin_amdgcn_mfma_f32_16x16x32_bf16(a01, bfr[ni][1], acc[2][ni], 0, 0, 0);
        acc[3][ni] = __builtin_amdgcn_mfma_f32_16x16x32_bf16(a10, bfr[ni][0], acc[3][ni], 0, 0, 0);
        acc[3][ni] = __builtin_amdgcn_mfma_f32_16x16x32_bf16(a11, bfr[ni][1], acc[3][ni], 0, 0, 0);
      }
      __builtin_amdgcn_s_setprio(0);
    }
    {
      bf16x8 a00 = loadA(buf, 4, 0), a01 = loadA(buf, 4, 1);
      bf16x8 a10 = loadA(buf, 5, 0), a11 = loadA(buf, 5, 1);
      __builtin_amdgcn_s_setprio(1);
#pragma unroll
      for (int ni = 0; ni < 4; ++ni) {
        acc[4][ni] = __builtin_amdgcn_mfma_f32_16x16x32_bf16(a00, bfr[ni][0], acc[4][ni], 0, 0, 0);
        acc[4][ni] = __builtin_amdgcn_mfma_f32_16x16x32_bf16(a01, bfr[ni][1], acc[4][ni], 0, 0, 0);
        acc[5][ni] = __builtin_amdgcn_mfma_f32_16x16x32_bf16(a10, bfr[ni][0], acc[5][ni], 0, 0, 0);
        acc[5][ni] = __builtin_amdgcn_mfma_f32_16x16x32_bf16(a11, bfr[ni][1], acc[5][ni], 0, 0, 0);
      }
      __builtin_amdgcn_s_setprio(0);
    }
    {
      bf16x8 a00 = loadA(buf, 6, 0), a01 = loadA(buf, 6, 1);
      bf16x8 a10 = loadA(buf, 7, 0), a11 = loadA(buf, 7, 1);
      __builtin_amdgcn_s_setprio(1);
#pragma unroll
      for (int ni = 0; ni < 4; ++ni) {
        acc[6][ni] = __builtin_amdgcn_mfma_f32_16x16x32_bf16(a00, bfr[ni][0], acc[6][ni], 0, 0, 0);
        acc[6][ni] = __builtin_amdgcn_mfma_f32_16x16x32_bf16(a01, bfr[ni][1], acc[6][ni], 0, 0, 0);
        acc[7][ni] = __builtin_amdgcn_mfma_f32_16x16x32_bf16(a10, bfr[ni][0], acc[7][ni], 0, 0, 0);
        acc[7][ni] = __builtin_amdgcn_mfma_f32_16x16x32_bf16(a11, bfr[ni][1], acc[7][ni], 0, 0, 0);
      }
      __builtin_amdgcn_s_setprio(0);
    }

    if (pre) {
      asm volatile("s_waitcnt vmcnt(0)" ::: "memory");
      __builtin_amdgcn_s_barrier();
      __builtin_amdgcn_sched_barrier(0);
    }
  }

  const int mb = bm + wr * 128 + hi * 4;
  const int nb = bn + wcn * 64 + lm;
  if (z == 1) {
#pragma unroll
    for (int ni = 0; ni < 4; ++ni) {
      const float bv_ = bias[nb + ni * 16];
#pragma unroll
      for (int mi = 0; mi < 8; ++mi)
#pragma unroll
        for (int r = 0; r < 4; ++r) {
          const float vv = fmaxf(acc[mi][ni][r] + bv_, 0.f);
          okp[kpack_off(mb + mi * 16 + r, nb + ni * 16)] = (bf16)vv;
        }
    }
  } else if (z == 2) {
#pragma unroll
    for (int ni = 0; ni < 4; ++ni) {
      const float bv_ = bias[nb + ni * 16];
#pragma unroll
      for (int mi = 0; mi < 8; ++mi)
#pragma unroll
        for (int r = 0; r < 4; ++r) {
          const float vv = fmaxf(acc[mi][ni][r] + bv_, 0.f);
          ovp[vpack_off(mb + mi * 16 + r, nb + ni * 16)] = (bf16)vv;
        }
    }
  } else {
    bf16* out = z == 0 ? oq : orr;
#pragma unroll
    for (int ni = 0; ni < 4; ++ni) {
      const float bv_ = bias[nb + ni * 16];
#pragma unroll
      for (int mi = 0; mi < 8; ++mi)
#pragma unroll
        for (int r = 0; r < 4; ++r) {
          const float vv = fmaxf(acc[mi][ni][r] + bv_, 0.f);
          out[(size_t)(mb + mi * 16 + r) * U + nb + ni * 16] = (bf16)vv;
        }
    }
  }
}

// ---------- flash attention: packed K/V, 2-buffer x 128-key big-tiles ----------
// 64 q-rows per wave (2 q-groups share fragment reads). TWO 64-key sub-tiles per
// barrier period: 16 barriers instead of 32, vmcnt(0) covered by ~2x compute span.
// Swapped QK^T (32x32x16); no-max softmax; osum via ones-MFMA; permlane half-exchange.
__global__ __launch_bounds__(256, 2) void attn_kernel(
    const bf16* __restrict__ Q, const bf16* __restrict__ Kp,
    const bf16* __restrict__ Vp, bf16* __restrict__ att) {
  const int bid = blockIdx.x;
  const int swz = (bid & 7) * 64 + (bid >> 3);     // 512 blocks, 8 per XCD chunk
  const int bh = swz >> 3, qx = swz & 7;
  const int b = bh >> 4, h = bh & 15;
  const int tid = threadIdx.x;
  const int w = tid >> 6, lane = tid & 63;
  const int l31 = lane & 31, hi8 = lane >> 5;
  const int q0 = qx * 256 + w * 64;

  __shared__ __align__(16) bf16 kv[2][16384];   // per buf: 2 sub-tiles x {K 4096 | V 4096}

  const float qscale = 0.18033688011111606f;  // log2(e)/sqrt(DH)

  bf16x8 qf[2][4];
#pragma unroll
  for (int qg = 0; qg < 2; ++qg) {
    const bf16* qbase = Q + ((size_t)b * S + q0 + qg * 32 + l31) * U + h * DH + hi8 * 8;
#pragma unroll
    for (int ks = 0; ks < 4; ++ks) {
      bf16x8 v = *reinterpret_cast<const bf16x8*>(qbase + ks * 16);
#pragma unroll
      for (int j = 0; j < 8; ++j) v[j] = (bf16)((float)v[j] * qscale);
      qf[qg][ks] = v;
    }
  }

  bf16x8 onesf;
#pragma unroll
  for (int j = 0; j < 8; ++j) onesf[j] = (bf16)1.f;

  f32x16 o[2][2], osum[2];
#pragma unroll
  for (int qg = 0; qg < 2; ++qg) {
    o[qg][0] = (f32x16)0.f; o[qg][1] = (f32x16)0.f; osum[qg] = (f32x16)0.f;
  }

  const bf16* kpb = Kp + (size_t)bh * 32 * 4096;
  const bf16* vpb = Vp + (size_t)bh * 32 * 4096;

  // stage one 128-key big-tile (2 sub-tiles) into buf
  auto stagekv2 = [&](int buf, int bt) {
#pragma unroll
    for (int st = 0; st < 2; ++st) {
      const size_t toff = (size_t)(bt * 2 + st) * 4096;
      bf16* base = &kv[buf][st * 8192];
      gload16(kpb + toff + tid * 8,        base + tid * 8);
      gload16(kpb + toff + 2048 + tid * 8, base + 2048 + tid * 8);
      gload16(vpb + toff + tid * 8,        base + 4096 + tid * 8);
      gload16(vpb + toff + 2048 + tid * 8, base + 6144 + tid * 8);
    }
  };

  stagekv2(0, 0);
  asm volatile("s_waitcnt vmcnt(0)" ::: "memory");
  __builtin_amdgcn_s_barrier();
  __builtin_amdgcn_sched_barrier(0);

  for (int bt = 0; bt < 16; ++bt) {
    const int buf = bt & 1;
    if (bt + 1 < 16) stagekv2(buf ^ 1, bt + 1);

#pragma unroll
    for (int st = 0; st < 2; ++st) {
      const bf16* sub = &kv[buf][st * 8192];

      // S^T = K Q^T for both q-groups; kf loaded in tt-halves to cap VGPR
      f32x16 s[2][2];
      s[0][0] = (f32x16)0.f; s[0][1] = (f32x16)0.f;
      s[1][0] = (f32x16)0.f; s[1][1] = (f32x16)0.f;
#pragma unroll
      for (int tt = 0; tt < 2; ++tt) {
        bf16x8 kf4[4];
#pragma unroll
        for (int ks = 0; ks < 4; ++ks)
          kf4[ks] = *reinterpret_cast<const bf16x8*>(sub + (tt * 4 + ks) * 512 + lane * 8);
        __builtin_amdgcn_s_setprio(1);
#pragma unroll
        for (int ks = 0; ks < 4; ++ks) {
          s[0][tt] = mfma32(kf4[ks], qf[0][ks], s[0][tt]);
          s[1][tt] = mfma32(kf4[ks], qf[1][ks], s[1][tt]);
        }
        __builtin_amdgcn_s_setprio(0);
      }

      // P = exp2(s); pack; half-exchange
      u32x4 fw[2][4];
#pragma unroll
      for (int qg = 0; qg < 2; ++qg) {
        unsigned wpk[16];
#pragma unroll
        for (int i = 0; i < 8; ++i) {
          wpk[i]     = packbf(fexp2(s[qg][0][2 * i]), fexp2(s[qg][0][2 * i + 1]));
          wpk[8 + i] = packbf(fexp2(s[qg][1][2 * i]), fexp2(s[qg][1][2 * i + 1]));
        }
#pragma unroll
        for (int fi = 0; fi < 4; ++fi) {
          unsigned a0 = wpk[fi * 4 + 0], b0 = wpk[fi * 4 + 2];
          unsigned a1 = wpk[fi * 4 + 1], b1 = wpk[fi * 4 + 3];
          asm("v_permlane32_swap_b32 %0, %1" : "+v"(a0), "+v"(b0));
          asm("v_permlane32_swap_b32 %0, %1" : "+v"(a1), "+v"(b1));
          fw[qg][fi] = u32x4{a0, a1, b0, b1};
        }
      }

      // O += P V (vf loaded in dt-halves); osum += P * ones
#pragma unroll
      for (int dt = 0; dt < 2; ++dt) {
        bf16x8 vf4[4];
#pragma unroll
        for (int ks = 0; ks < 4; ++ks)
          vf4[ks] = *reinterpret_cast<const bf16x8*>(sub + 4096 + (dt * 4 + ks) * 512 + lane * 8);
        __builtin_amdgcn_s_setprio(1);
#pragma unroll
        for (int ks = 0; ks < 4; ++ks) {
          o[0][dt] = mfma32(__builtin_bit_cast(bf16x8, fw[0][ks]), vf4[ks], o[0][dt]);
          o[1][dt] = mfma32(__builtin_bit_cast(bf16x8, fw[1][ks]), vf4[ks], o[1][dt]);
        }
        __builtin_amdgcn_s_setprio(0);
      }
      __builtin_amdgcn_s_setprio(1);
#pragma unroll
      for (int ks = 0; ks < 4; ++ks) {
        osum[0] = mfma32(__builtin_bit_cast(bf16x8, fw[0][ks]), onesf, osum[0]);
        osum[1] = mfma32(__builtin_bit_cast(bf16x8, fw[1][ks]), onesf, osum[1]);
      }
      __builtin_amdgcn_s_setprio(0);
    }

    if (bt + 1 < 16) {
      asm volatile("s_waitcnt vmcnt(0)" ::: "memory");
      __builtin_amdgcn_s_barrier();
      __builtin_amdgcn_sched_barrier(0);
    }
  }

  // normalize + store
#pragma unroll
  for (int qg = 0; qg < 2; ++qg) {
    bf16* obase = att + ((size_t)b * S + q0 + qg * 32) * U + h * DH + l31;
#pragma unroll
    for (int r = 0; r < 16; ++r) {
      const int row = (r & 3) + 8 * (r >> 2) + 4 * hi8;
      const float lr = 1.f / osum[qg][r];
      obase[(size_t)row * U]      = (bf16)(o[qg][0][r] * lr);
      obase[(size_t)row * U + 32] = (bf16)(o[qg][1][r] * lr);
    }
  }
}

// ---------- epilogue: x = relu(att + vres); LayerNorm(x)*gamma + beta ----------
__global__ __launch_bounds__(256) void ln_kernel(
    const bf16* __restrict__ att, const bf16* __restrict__ vres,
    const float* __restrict__ gamma, const float* __restrict__ beta,
    float* __restrict__ out) {
  const int w = threadIdx.x >> 6, lane = threadIdx.x & 63;
  const int row = blockIdx.x * 4 + w;
  const int c0 = lane * 16;
  const bf16* ar = att  + (size_t)row * U + c0;
  const bf16* vr = vres + (size_t)row * U + c0;

  const bf16x8 a0 = *reinterpret_cast<const bf16x8*>(ar);
  const bf16x8 a1 = *reinterpret_cast<const bf16x8*>(ar + 8);
  const bf16x8 v0 = *reinterpret_cast<const bf16x8*>(vr);
  const bf16x8 v1 = *reinterpret_cast<const bf16x8*>(vr + 8);

  float x[16];
  float sum = 0.f, sq = 0.f;
#pragma unroll
  for (int i = 0; i < 8; ++i) {
    x[i]     = fmaxf((float)a0[i] + (float)v0[i], 0.f);
    x[8 + i] = fmaxf((float)a1[i] + (float)v1[i], 0.f);
  }
#pragma unroll
  for (int i = 0; i < 16; ++i) { sum += x[i]; sq += x[i] * x[i]; }
#pragma unroll
  for (int mm = 1; mm < 64; mm <<= 1) {
    sum += __shfl_xor(sum, mm);
    sq  += __shfl_xor(sq, mm);
  }
  const float mean = sum * (1.f / U);
  float var = sq * (1.f / U) - mean * mean;
  var = fmaxf(var, 0.f);
  const float inv = rsqrtf(var + 1e-8f);

  float* orow = out + (size_t)row * U + c0;
#pragma unroll
  for (int j = 0; j < 4; ++j) {
    const float4 g = *reinterpret_cast<const float4*>(gamma + c0 + j * 4);
    const float4 bt = *reinterpret_cast<const float4*>(beta + c0 + j * 4);
    float4 o;
    o.x = g.x * ((x[j * 4 + 0] - mean) * inv) + bt.x;
    o.y = g.y * ((x[j * 4 + 1] - mean) * inv) + bt.y;
    o.z = g.z * ((x[j * 4 + 2] - mean) * inv) + bt.z;
    o.w = g.w * ((x[j * 4 + 3] - mean) * inv) + bt.w;
    *reinterpret_cast<float4*>(orow + j * 4) = o;
  }
}

extern "C" void kernel_launch(void* const* d_in, const int* in_sizes, int n_in,
                              void* d_out, int out_size, void* d_ws, size_t ws_size,
                              hipStream_t stream) {
  const float* queries = (const float*)d_in[0];
  const float* keys    = (const float*)d_in[1];
  const float* values  = (const float*)d_in[2];
  const float* Wq = (const float*)d_in[3];
  const float* bq = (const float*)d_in[4];
  const float* Wk = (const float*)d_in[5];
  const float* bk = (const float*)d_in[6];
  const float* Wv = (const float*)d_in[7];
  const float* bv = (const float*)d_in[8];
  const float* Wr = (const float*)d_in[9];
  const float* br = (const float*)d_in[10];
  const float* gamma = (const float*)d_in[11];
  const float* beta  = (const float*)d_in[12];
  float* out = (float*)d_out;

  char* ws = (char*)d_ws;
  const size_t MB = 1024 * 1024;
  bf16* wqt  = (bf16*)(ws + 0 * MB);
  bf16* wkt  = (bf16*)(ws + 2 * MB);
  bf16* wvt  = (bf16*)(ws + 4 * MB);
  bf16* wrt  = (bf16*)(ws + 6 * MB);
  bf16* Qcvt = (bf16*)(ws + 8 * MB);    // dead after gemm -> attb aliases
  bf16* Kcvt = (bf16*)(ws + 24 * MB);   // dead after gemm -> Rb aliases (Rb written by gemm z=3)
  bf16* Vcvt = (bf16*)(ws + 40 * MB);
  bf16* Qb   = (bf16*)(ws + 56 * MB);
  bf16* Kp   = (bf16*)(ws + 72 * MB);
  bf16* Vp   = (bf16*)(ws + 88 * MB);   // total 104 MB
  bf16* attb = Qcvt;
  bf16* Rb   = Kcvt;

  prep_kernel<<<dim3(16384), 256, 0, stream>>>(
      queries, keys, values, Qcvt, Kcvt, Vcvt,
      Wq, Wk, Wv, Wr, wqt, wkt, wvt, wrt);
  gemm4_kernel<<<dim3(512), 512, 0, stream>>>(
      Qcvt, Kcvt, Vcvt, wqt, wkt, wvt, wrt, bq, bk, bv, br, Qb, Kp, Vp, Rb);
  attn_kernel<<<dim3(512), 256, 0, stream>>>(Qb, Kp, Vp, attb);
  ln_kernel<<<dim3(MTOT / 4), 256, 0, stream>>>(attb, Rb, gamma, beta, out);
}